// Round 8
// baseline (881.082 us; speedup 1.0000x reference)
//
#include <hip/hip_runtime.h>
#include <math.h>

#define V_NODES 3000
#define K_DEG 16
#define E_EDGES 48000
#define H 256
#define TE 128
#define L_LAYERS 12

typedef __attribute__((ext_vector_type(4))) float f32x4;
typedef __attribute__((ext_vector_type(8))) __bf16 bf16x8;
typedef __attribute__((ext_vector_type(4))) unsigned short u16x4;

__device__ __forceinline__ unsigned short f2bf(float f) {
  unsigned u = __float_as_uint(f);
  unsigned r = (u + 0x7fffu + ((u >> 16) & 1u)) >> 16;
  return (unsigned short)r;
}

__device__ __forceinline__ float bf2f(unsigned short u) {
  return __uint_as_float(((unsigned)u) << 16);
}

// fast sigmoid: 1/(1+2^(-x*log2e)) via v_exp_f32 + v_rcp_f32 (~1e-6 rel err)
__device__ __forceinline__ float fsig(float x) {
  return __builtin_amdgcn_rcpf(1.0f + __builtin_amdgcn_exp2f(-1.4426950408889634f * x));
}

__device__ __forceinline__ void gload16(const void* g, void* l) {
  __builtin_amdgcn_global_load_lds((const __attribute__((address_space(1))) void*)g,
                                   (__attribute__((address_space(3))) void*)l, 16, 0, 0);
}

// ---------------------------------------------------------------------------
// Weight prep: transpose 256x256 f32 [k][n] -> bf16 [n][k]; UVAB packed to
// [1024][256] per layer.
// ---------------------------------------------------------------------------
__global__ __launch_bounds__(256) void k_prep_w(const float* __restrict__ U_w, const float* __restrict__ V_w,
                                                const float* __restrict__ A_w, const float* __restrict__ B_w,
                                                const float* __restrict__ C_w, const float* __restrict__ plo_w,
                                                const float* __restrict__ edge_w,
                                                unsigned short* __restrict__ WT4, unsigned short* __restrict__ WTC,
                                                unsigned short* __restrict__ WTplo, unsigned short* __restrict__ WTedge) {
  int bid = blockIdx.x;
  const float* src;
  unsigned short* dst;
  int tt;
  if (bid < 768) {
    int l = bid >> 6;
    int rem = bid & 63;
    int mat = rem >> 4;
    tt = rem & 15;
    const float* srcs[4] = {U_w, V_w, A_w, B_w};
    src = srcs[mat] + (size_t)l * H * H;
    dst = WT4 + (size_t)l * 1024 * H + (size_t)mat * H * H;
  } else if (bid < 960) {
    int b2 = bid - 768;
    int l = b2 >> 4;
    tt = b2 & 15;
    src = C_w + (size_t)l * H * H;
    dst = WTC + (size_t)l * H * H;
  } else if (bid < 1152) {
    int b2 = bid - 960;
    int l = b2 >> 4;
    tt = b2 & 15;
    src = plo_w + (size_t)l * H * H;
    dst = WTplo + (size_t)l * H * H;
  } else {
    tt = bid - 1152;
    src = edge_w;
    dst = WTedge;
  }
  int k0 = (tt & 3) * 64, n0 = (tt >> 2) * 64;
  __shared__ float ts[64][65];
  int c = threadIdx.x & 63;
  int r0 = threadIdx.x >> 6;
  for (int rr = 0; rr < 64; rr += 4) {
    int r = rr + r0;
    ts[r][c] = src[(size_t)(k0 + r) * H + n0 + c];
  }
  __syncthreads();
  for (int nn = 0; nn < 64; nn += 4) {
    int n = nn + r0;
    dst[(size_t)(n0 + n) * H + k0 + c] = f2bf(ts[c][n]);
  }
}

__global__ __launch_bounds__(256) void k_prep_b(const float* __restrict__ U_b, const float* __restrict__ V_b,
                                                const float* __restrict__ A_b, const float* __restrict__ B_b,
                                                float* __restrict__ b4) {
  int l = blockIdx.x;
  int t = threadIdx.x;
  b4[l * 1024 + 0 + t] = U_b[l * H + t];
  b4[l * 1024 + 256 + t] = V_b[l * H + t];
  b4[l * 1024 + 512 + t] = A_b[l * H + t];
  b4[l * 1024 + 768 + t] = B_b[l * H + t];
}

// ---------------------------------------------------------------------------
// Plain MFMA GEMM (128x128 tile, 4 waves, BK=64).
// MODE 0: node UVAB -> n<256: Uh f32[m*256+n]; else XWb bf16[m*768+n-256]
// MODE 2: edge plo  -> e_bf += acc + bias (bf16 storage); GN: fused stats
// MODE 3: edge embed-> acc + bias + mask_emb[mask[m]] -> e_bf
// ---------------------------------------------------------------------------
template <int MODE, bool GN>
__global__ __launch_bounds__(256) void k_gemm(const unsigned short* __restrict__ A,
                                              const unsigned short* __restrict__ WT,
                                              int M,
                                              const float* __restrict__ bias,
                                              const int* __restrict__ maskp,
                                              const float* __restrict__ mask_emb,
                                              float* __restrict__ out_f32,
                                              unsigned short* __restrict__ out_bf16,
                                              double* __restrict__ gnp) {
  const int t = threadIdx.x;
  const int m0 = blockIdx.x * 128;
  const int nb = blockIdx.y * 128;
  const int lane = t & 63;
  const int wave = t >> 6;
  const int wr = wave >> 1, wc = wave & 1;
  const int lrow = lane & 15, lg = lane >> 4;

  __shared__ __align__(16) char lds[32768];
  char* Als = lds;
  char* Bls = lds + 16384;

  f32x4 acc[4][4];
#pragma unroll
  for (int i = 0; i < 4; ++i)
#pragma unroll
    for (int j = 0; j < 4; ++j) acc[i][j] = (f32x4)0.0f;

  for (int kt = 0; kt < 4; ++kt) {
    const int k0b = kt * 128;
#pragma unroll
    for (int i = 0; i < 4; ++i) {
      int o = i * 4096 + t * 16;
      int row = o >> 7;
      int cb = o & 127;
      int cbl = cb ^ ((row & 7) << 4);
      int rA = m0 + row;
      rA = rA < M ? rA : 0;
      gload16((const char*)A + (size_t)rA * 512 + k0b + cbl,
              Als + i * 4096 + (t & 192) * 16);
      gload16((const char*)WT + (size_t)(nb + row) * 512 + k0b + cbl,
              Bls + i * 4096 + (t & 192) * 16);
    }
    __syncthreads();
#pragma unroll
    for (int ks = 0; ks < 2; ++ks) {
      bf16x8 af[4], bfv[4];
#pragma unroll
      for (int mi = 0; mi < 4; ++mi) {
        int ra = wr * 64 + mi * 16 + lrow;
        int cba = (ks * 64 + lg * 16) ^ ((ra & 7) << 4);
        af[mi] = *(const bf16x8*)(Als + ra * 128 + cba);
        int rb = wc * 64 + mi * 16 + lrow;
        int cbb = (ks * 64 + lg * 16) ^ ((rb & 7) << 4);
        bfv[mi] = *(const bf16x8*)(Bls + rb * 128 + cbb);
      }
#pragma unroll
      for (int mi = 0; mi < 4; ++mi)
#pragma unroll
        for (int ni = 0; ni < 4; ++ni)
          acc[mi][ni] = __builtin_amdgcn_mfma_f32_16x16x32_bf16(af[mi], bfv[ni], acc[mi][ni], 0, 0, 0);
    }
    __syncthreads();
  }

  double ps[4] = {0, 0, 0, 0}, pq[4] = {0, 0, 0, 0};
#pragma unroll
  for (int mi = 0; mi < 4; ++mi) {
#pragma unroll
    for (int r = 0; r < 4; ++r) {
      int m = m0 + wr * 64 + mi * 16 + lg * 4 + r;
      if (MODE == 0 && m >= M) continue;
      int mk = 0;
      if constexpr (MODE == 3) { mk = maskp[m]; }
#pragma unroll
      for (int ni = 0; ni < 4; ++ni) {
        int n = nb + wc * 64 + ni * 16 + lrow;
        float v = acc[mi][ni][r] + bias[n];
        if constexpr (MODE == 0) {
          if (n < 256) out_f32[(size_t)m * 256 + n] = v;                 // Uh f32
          else out_bf16[(size_t)m * 768 + (n - 256)] = f2bf(v);          // V/A/B bf16
        } else if constexpr (MODE == 2) {
          float eo = bf2f(out_bf16[(size_t)m * 256 + n]);
          unsigned short nb16 = f2bf(eo + v);
          out_bf16[(size_t)m * 256 + n] = nb16;
          if constexpr (GN) {
            float rv = bf2f(nb16);
            ps[ni] += (double)rv;
            pq[ni] += (double)rv * (double)rv;
          }
        } else {
          v += mask_emb[mk * 256 + n];
          out_bf16[(size_t)m * 256 + n] = f2bf(v);
        }
      }
    }
  }

  if constexpr (GN) {
    __syncthreads();
    double* redS = (double*)lds;           // [128][8] f64 = 8KB
    double* redQ = (double*)(lds + 8192);  // 8KB
    int slot = wr * 4 + lg;
#pragma unroll
    for (int ni = 0; ni < 4; ++ni) {
      int cn = wc * 64 + ni * 16 + lrow;
      redS[cn * 8 + slot] = ps[ni];
      redQ[cn * 8 + slot] = pq[ni];
    }
    __syncthreads();
    if (t < 128) {
      double s = 0, q = 0;
#pragma unroll
      for (int k = 0; k < 8; ++k) { s += redS[t * 8 + k]; q += redQ[t * 8 + k]; }
      atomicAdd(&gnp[nb + t], s);
      atomicAdd(&gnp[H + nb + t], q);
    }
  }
}

// ---------------------------------------------------------------------------
// Fused layer-edge kernel v4: BM=32 (2 nodes), BN=256, 8 waves (512 thr).
// LDS = max(A 4K + B 32K, enew 32x256 f32) = 36KB -> 4 blocks/CU.
// Node mats: Uh f32 [V][256]; XWb bf16 [V][768] = V|A|B (gathers halved).
// E0: acc + Cb + Ah[col] + Bh[row] -> enew (XOR-swizzled f32)
// E1: node update (waves 0-1, one node each)
// E2: double-LN+silu -> bout bf16 (all 8 waves, 4 rows each)
// ---------------------------------------------------------------------------
__global__ __launch_bounds__(512, 8) void k_layer_edge(const unsigned short* __restrict__ A,
                                                       const unsigned short* __restrict__ WT,
                                                       const float* __restrict__ Cb,
                                                       const int* __restrict__ ei_col,
                                                       const float* __restrict__ Uh,
                                                       const unsigned short* __restrict__ XWb,
                                                       const float* __restrict__ nhg, const float* __restrict__ nhb,
                                                       const float* __restrict__ neg_, const float* __restrict__ neb_,
                                                       const float* __restrict__ tvec_l,
                                                       const float* __restrict__ pg_, const float* __restrict__ pb_,
                                                       float* __restrict__ x, unsigned short* __restrict__ xb,
                                                       unsigned short* __restrict__ bout) {
  const int t = threadIdx.x;
  const int m0 = blockIdx.x * 32;
  const int lane = t & 63;
  const int wave = t >> 6;      // 8 col-groups of 32 cols each
  const int wc = wave;
  const int lrow = lane & 15, lg = lane >> 4;
  const int c0 = lane * 4;

  __shared__ __align__(16) char lds[36864];
  char* Als = lds;            // [32][128B] swizzled (GEMM phase)
  char* Bls = lds + 4096;     // [256][128B] swizzled (GEMM phase)
  float* enew = (float*)lds;  // [32][256] f32 swizzled (epilogue)

  f32x4 acc[2][2];
#pragma unroll
  for (int i = 0; i < 2; ++i)
#pragma unroll
    for (int j = 0; j < 2; ++j) acc[i][j] = (f32x4)0.0f;

  const int wave_off = wave * 1024;
  for (int kt = 0; kt < 4; ++kt) {
    const int k0b = kt * 128;
    if (t < 256) {  // A: 32 rows x 128B = 4KB
      int o = t * 16;
      int row = o >> 7;
      int cbl = (o & 127) ^ ((row & 7) << 4);
      gload16((const char*)A + (size_t)(m0 + row) * 512 + k0b + cbl, Als + wave_off);
    }
#pragma unroll
    for (int c = 0; c < 4; ++c) {  // B: 256 rows x 128B = 32KB
      int o = c * 8192 + t * 16;
      int row = o >> 7;
      int cbl = (o & 127) ^ ((row & 7) << 4);
      gload16((const char*)WT + (size_t)row * 512 + k0b + cbl, Bls + c * 8192 + wave_off);
    }
    __syncthreads();
#pragma unroll
    for (int ks = 0; ks < 2; ++ks) {
      bf16x8 af[2], bfv[2];
#pragma unroll
      for (int mi = 0; mi < 2; ++mi) {
        int ra = mi * 16 + lrow;
        af[mi] = *(const bf16x8*)(Als + ra * 128 + ((ks * 64 + lg * 16) ^ ((ra & 7) << 4)));
      }
#pragma unroll
      for (int ni = 0; ni < 2; ++ni) {
        int rb = wc * 32 + ni * 16 + lrow;
        bfv[ni] = *(const bf16x8*)(Bls + rb * 128 + ((ks * 64 + lg * 16) ^ ((rb & 7) << 4)));
      }
#pragma unroll
      for (int mi = 0; mi < 2; ++mi)
#pragma unroll
        for (int ni = 0; ni < 2; ++ni)
          acc[mi][ni] = __builtin_amdgcn_mfma_f32_16x16x32_bf16(af[mi], bfv[ni], acc[mi][ni], 0, 0, 0);
    }
    __syncthreads();
  }

  // ---- E0: acc + Cb + Ah[col] + Bh[node] -> enew (swizzled f32) ----
  {
    float bs[2];
#pragma unroll
    for (int ni = 0; ni < 2; ++ni) bs[ni] = Cb[wc * 32 + ni * 16 + lrow];
#pragma unroll
    for (int mi = 0; mi < 2; ++mi) {
#pragma unroll
      for (int r = 0; r < 4; ++r) {
        int ml = mi * 16 + lg * 4 + r;
        int m = m0 + ml;
        int cv = ei_col[m];
        const unsigned short* AhR = XWb + (size_t)cv * 768 + 256;
        const unsigned short* BhR = XWb + (size_t)(m >> 4) * 768 + 512;
        int sw = (ml & 15) << 2;
#pragma unroll
        for (int ni = 0; ni < 2; ++ni) {
          int n = wc * 32 + ni * 16 + lrow;
          enew[ml * 256 + (n ^ sw)] = acc[mi][ni][r] + bs[ni] + bf2f(AhR[n]) + bf2f(BhR[n]);
        }
      }
    }
  }
  __syncthreads();

  // ---- E1: node update (waves 0-1, one node each) ----
  if (wave < 2) {
    int v = (m0 >> 4) + wave;
    f32x4 agg = (f32x4)0.0f;
#pragma unroll 4
    for (int k = 0; k < K_DEG; ++k) {
      int row = wave * 16 + k;
      int cv = ei_col[m0 + row];
      f32x4 en = *(const f32x4*)&enew[row * 256 + (c0 ^ ((row & 15) << 2))];
      u16x4 vhu = *(const u16x4*)&XWb[(size_t)cv * 768 + c0];
#pragma unroll
      for (int i = 0; i < 4; ++i) agg[i] += bf2f(vhu[i]) * fsig(en[i]);
    }
    f32x4 s4 = *(const f32x4*)&Uh[(size_t)v * 256 + c0];
    s4 += agg;
    float s = s4[0] + s4[1] + s4[2] + s4[3];
    float sq = s4[0] * s4[0] + s4[1] * s4[1] + s4[2] * s4[2] + s4[3] * s4[3];
#pragma unroll
    for (int st = 1; st < 64; st <<= 1) { s += __shfl_xor(s, st); sq += __shfl_xor(sq, st); }
    float mean = s * (1.0f / H);
    float inv = rsqrtf(sq * (1.0f / H) - mean * mean + 1e-5f);
    f32x4 g = *(const f32x4*)&nhg[c0];
    f32x4 bb = *(const f32x4*)&nhb[c0];
    f32x4 xo = *(const f32x4*)&x[(size_t)v * H + c0];
    u16x4 ov;
#pragma unroll
    for (int i = 0; i < 4; ++i) {
      float h = fmaxf((s4[i] - mean) * inv * g[i] + bb[i], 0.0f);
      xo[i] += h;
      ov[i] = f2bf(xo[i]);
    }
    *(f32x4*)&x[(size_t)v * H + c0] = xo;
    *(u16x4*)&xb[(size_t)v * H + c0] = ov;
  }

  // ---- E2: double-LN + silu chain -> bout bf16 (4 rows per wave) ----
  {
    f32x4 g1 = *(const f32x4*)&neg_[c0];
    f32x4 b1 = *(const f32x4*)&neb_[c0];
    f32x4 tv = *(const f32x4*)&tvec_l[c0];
    f32x4 g2 = *(const f32x4*)&pg_[c0];
    f32x4 b2 = *(const f32x4*)&pb_[c0];
#pragma unroll
    for (int k = 0; k < 4; ++k) {
      int row = wave + 8 * k;
      f32x4 vv = *(const f32x4*)&enew[row * 256 + (c0 ^ ((row & 15) << 2))];
      float s = vv[0] + vv[1] + vv[2] + vv[3];
      float sq = vv[0] * vv[0] + vv[1] * vv[1] + vv[2] * vv[2] + vv[3] * vv[3];
#pragma unroll
      for (int st = 1; st < 64; st <<= 1) { s += __shfl_xor(s, st); sq += __shfl_xor(sq, st); }
      float mean = s * (1.0f / H);
      float inv = rsqrtf(sq * (1.0f / H) - mean * mean + 1e-5f);
      f32x4 a;
#pragma unroll
      for (int i = 0; i < 4; ++i) a[i] = fmaxf((vv[i] - mean) * inv * g1[i] + b1[i], 0.0f) + tv[i];
      s = a[0] + a[1] + a[2] + a[3];
      sq = a[0] * a[0] + a[1] * a[1] + a[2] * a[2] + a[3] * a[3];
#pragma unroll
      for (int st = 1; st < 64; st <<= 1) { s += __shfl_xor(s, st); sq += __shfl_xor(sq, st); }
      mean = s * (1.0f / H);
      inv = rsqrtf(sq * (1.0f / H) - mean * mean + 1e-5f);
      u16x4 ov;
#pragma unroll
      for (int i = 0; i < 4; ++i) {
        float n = (a[i] - mean) * inv * g2[i] + b2[i];
        ov[i] = f2bf(n * fsig(n));
      }
      *(u16x4*)&bout[(size_t)(m0 + row) * H + c0] = ov;
    }
  }
}

// ---------------------------------------------------------------------------
// Node positional embedding + node_w matmul
// ---------------------------------------------------------------------------
__global__ __launch_bounds__(256) void k_node_embed(const float* __restrict__ coords,
                                                    const float* __restrict__ W,
                                                    const float* __restrict__ b,
                                                    float* __restrict__ x,
                                                    unsigned short* __restrict__ xb) {
  int v = blockIdx.x;
  int j = threadIdx.x;
  __shared__ float4 pe4[H / 4];
  float cy = coords[v * 2 + 0] * 6.283185307179586f;
  float cx = coords[v * 2 + 1] * 6.283185307179586f;
  int idx = j & 127;
  float coord = (j < 128) ? cy : cx;
  float dim_t = powf(10000.0f, (2.0f * (float)(idx >> 1)) / 128.0f);
  float val = coord / dim_t;
  ((float*)pe4)[j] = (idx & 1) ? cosf(val) : sinf(val);
  __syncthreads();
  float acc = b[j];
  for (int k4 = 0; k4 < H / 4; ++k4) {
    float4 p = pe4[k4];
    int k = 4 * k4;
    acc += p.x * W[(k + 0) * H + j] + p.y * W[(k + 1) * H + j] +
           p.z * W[(k + 2) * H + j] + p.w * W[(k + 3) * H + j];
  }
  x[(size_t)v * H + j] = acc;
  xb[(size_t)v * H + j] = f2bf(acc);
}

// ---------------------------------------------------------------------------
// Edge scalar sine embedding -> pe bf16
// ---------------------------------------------------------------------------
__global__ __launch_bounds__(256) void k_pe(const float* __restrict__ e_vals, unsigned short* __restrict__ pe) {
  int eid = blockIdx.x * 4 + (threadIdx.x >> 6);
  int lane = threadIdx.x & 63;
  int c0 = lane * 4;
  float val = e_vals[eid];
  const float lg = 13.287712379549449f / 256.0f;
  u16x4 ov;
#pragma unroll
  for (int i = 0; i < 4; ++i) {
    int c = c0 + i;
    float invd = exp2f(-(float)(c & ~1) * lg);
    float arg = val * invd;
    float s = (c & 1) ? cosf(arg) : sinf(arg);
    ov[i] = f2bf(s);
  }
  *(u16x4*)&pe[(size_t)eid * H + c0] = ov;
}

// ---------------------------------------------------------------------------
// Timestep embedding MLP + per-layer conditioning
// ---------------------------------------------------------------------------
__global__ __launch_bounds__(256) void k_temb(const int* __restrict__ t,
                                              const float* __restrict__ te1_w, const float* __restrict__ te1_b,
                                              const float* __restrict__ te2_w, const float* __restrict__ te2_b,
                                              float* __restrict__ temb_out) {
  __shared__ float emb[H];
  __shared__ float h1[TE];
  int j = threadIdx.x;
  float tv = (float)t[0];
  {
    int i = j & 127;
    float f = expf(-logf(10000.0f) * (float)i / 128.0f);
    float arg = tv * f;
    emb[j] = (j < 128) ? cosf(arg) : sinf(arg);
  }
  __syncthreads();
  if (j < TE) {
    float acc = te1_b[j];
    for (int k = 0; k < H; ++k) acc += emb[k] * te1_w[k * TE + j];
    h1[j] = fmaxf(acc, 0.0f);
  }
  __syncthreads();
  if (j < TE) {
    float acc = te2_b[j];
    for (int k = 0; k < TE; ++k) acc += h1[k] * te2_w[k * TE + j];
    temb_out[j] = acc;
  }
}

__global__ __launch_bounds__(256) void k_tvec(const float* __restrict__ temb,
                                              const float* __restrict__ tl_w, const float* __restrict__ tl_b,
                                              float* __restrict__ tvec) {
  int l = blockIdx.x;
  int j = threadIdx.x;
  __shared__ float rt[TE];
  if (j < TE) rt[j] = fmaxf(temb[j], 0.0f);
  __syncthreads();
  float acc = tl_b[l * H + j];
  for (int k = 0; k < TE; ++k) acc += rt[k] * tl_w[(size_t)(l * TE + k) * H + j];
  tvec[l * H + j] = acc;
}

__global__ void k_gn_finalize(const double* __restrict__ sums, float* __restrict__ gstats) {
  int g = threadIdx.x;
  if (g < 32) {
    double s = 0.0, sq = 0.0;
    for (int c = g * 8; c < g * 8 + 8; ++c) {
      s += sums[c];
      sq += sums[H + c];
    }
    double n = 8.0 * (double)E_EDGES;
    double mean = s / n;
    double var = sq / n - mean * mean;
    gstats[g] = (float)mean;
    gstats[32 + g] = (float)(1.0 / sqrt(var + 1e-5));
  }
}

__global__ __launch_bounds__(256) void k_head(const unsigned short* __restrict__ e_bf,
                                              const float* __restrict__ gstats,
                                              const float* __restrict__ gn_g, const float* __restrict__ gn_b,
                                              const float* __restrict__ out_w, const float* __restrict__ out_b,
                                              float* __restrict__ out) {
  int wv = threadIdx.x >> 6;
  int lane = threadIdx.x & 63;
  int eid = blockIdx.x * 4 + wv;
  int c0 = lane * 4;
  u16x4 ev = *(const u16x4*)&e_bf[(size_t)eid * H + c0];
  float a0 = 0.0f, a1 = 0.0f;
#pragma unroll
  for (int i = 0; i < 4; ++i) {
    int c = c0 + i;
    int g = c >> 3;
    float v = (bf2f(ev[i]) - gstats[g]) * gstats[32 + g] * gn_g[c] + gn_b[c];
    v = fmaxf(v, 0.0f);
    a0 += v * out_w[c * 2 + 0];
    a1 += v * out_w[c * 2 + 1];
  }
  for (int s = 32; s > 0; s >>= 1) {
    a0 += __shfl_down(a0, s);
    a1 += __shfl_down(a1, s);
  }
  if (lane == 0) {
    out[(size_t)eid * 2 + 0] = a0 + out_b[0];
    out[(size_t)eid * 2 + 1] = a1 + out_b[1];
  }
}

// ---------------------------------------------------------------------------
extern "C" void kernel_launch(void* const* d_in, const int* in_sizes, int n_in,
                              void* d_out, int out_size, void* d_ws, size_t ws_size,
                              hipStream_t stream) {
  const float* nodes_feature = (const float*)d_in[0];
  const float* e_vals = (const float*)d_in[1];
  const int* mask = (const int*)d_in[2];
  const int* t = (const int*)d_in[3];
  const int* edge_index = (const int*)d_in[4];
  const float* node_w = (const float*)d_in[5];
  const float* node_b = (const float*)d_in[6];
  const float* edge_w = (const float*)d_in[7];
  const float* edge_b = (const float*)d_in[8];
  const float* te1_w = (const float*)d_in[9];
  const float* te1_b = (const float*)d_in[10];
  const float* te2_w = (const float*)d_in[11];
  const float* te2_b = (const float*)d_in[12];
  const float* U_w = (const float*)d_in[13];
  const float* U_b = (const float*)d_in[14];
  const float* V_w = (const float*)d_in[15];
  const float* V_b = (const float*)d_in[16];
  const float* A_w = (const float*)d_in[17];
  const float* A_b = (const float*)d_in[18];
  const float* B_w = (const float*)d_in[19];
  const float* B_b = (const float*)d_in[20];
  const float* C_w = (const float*)d_in[21];
  const float* C_b = (const float*)d_in[22];
  const float* nh_g = (const float*)d_in[23];
  const float* nh_b = (const float*)d_in[24];
  const float* ne_g = (const float*)d_in[25];
  const float* ne_b = (const float*)d_in[26];
  const float* tl_w = (const float*)d_in[27];
  const float* tl_b = (const float*)d_in[28];
  const float* plo_g = (const float*)d_in[29];
  const float* plo_b = (const float*)d_in[30];
  const float* plo_w = (const float*)d_in[31];
  const float* plo_b2 = (const float*)d_in[32];
  const float* gn_g = (const float*)d_in[33];
  const float* gn_b = (const float*)d_in[34];
  const float* out_w = (const float*)d_in[35];
  const float* out_b = (const float*)d_in[36];
  const float* mask_emb = (const float*)d_in[37];

  char* wsb = (char*)d_ws;
  size_t off = 0;
  auto alloc = [&](size_t bytes) -> void* {
    void* p = wsb + off;
    off += (bytes + 255) & ~(size_t)255;
    return p;
  };
  double* gn_sums = (double*)alloc(512 * sizeof(double));
  float* Uh = (float*)alloc((size_t)V_NODES * H * 4);
  unsigned short* XWb = (unsigned short*)alloc((size_t)V_NODES * 768 * 2);
  unsigned short* e_bf = (unsigned short*)alloc((size_t)E_EDGES * H * 2);
  unsigned short* pe_b = (unsigned short*)alloc((size_t)E_EDGES * H * 2);
  unsigned short* x_bf = (unsigned short*)alloc((size_t)V_NODES * H * 2);
  unsigned short* WT4 = (unsigned short*)alloc((size_t)L_LAYERS * 1024 * H * 2);
  unsigned short* WTC = (unsigned short*)alloc((size_t)L_LAYERS * H * H * 2);
  unsigned short* WTplo = (unsigned short*)alloc((size_t)L_LAYERS * H * H * 2);
  unsigned short* WTedge = (unsigned short*)alloc((size_t)H * H * 2);
  float* b4 = (float*)alloc((size_t)L_LAYERS * 1024 * 4);
  float* temb = (float*)alloc(TE * 4);
  float* tvec = (float*)alloc((size_t)L_LAYERS * H * 4);
  float* gstats = (float*)alloc(64 * 4);

  const int* ei_col = edge_index + E_EDGES;

  float* x = (float*)d_out;
  float* out2 = (float*)d_out + (size_t)V_NODES * H;

  k_prep_w<<<1168, 256, 0, stream>>>(U_w, V_w, A_w, B_w, C_w, plo_w, edge_w, WT4, WTC, WTplo, WTedge);
  k_prep_b<<<L_LAYERS, 256, 0, stream>>>(U_b, V_b, A_b, B_b, b4);
  k_node_embed<<<V_NODES, 256, 0, stream>>>(nodes_feature, node_w, node_b, x, x_bf);
  k_pe<<<E_EDGES / 4, 256, 0, stream>>>(e_vals, pe_b);
  k_temb<<<1, 256, 0, stream>>>(t, te1_w, te1_b, te2_w, te2_b, temb);
  k_tvec<<<L_LAYERS, 256, 0, stream>>>(temb, tl_w, tl_b, tvec);
  k_gemm<3, false><<<dim3(E_EDGES / 128, 2), 256, 0, stream>>>(pe_b, WTedge, E_EDGES, edge_b, mask, mask_emb,
                                                               nullptr, e_bf, nullptr);
  hipMemsetAsync(gn_sums, 0, 512 * sizeof(double), stream);

  for (int l = 0; l < L_LAYERS; ++l) {
    size_t wo = (size_t)l * H * H;
    size_t bo = (size_t)l * H;
    k_gemm<0, false><<<dim3(24, 8), 256, 0, stream>>>(x_bf, WT4 + (size_t)l * 1024 * H, V_NODES, b4 + l * 1024,
                                                      nullptr, nullptr, Uh, XWb, nullptr);
    k_layer_edge<<<E_EDGES / 32, 512, 0, stream>>>(e_bf, WTC + wo, C_b + bo, ei_col, Uh, XWb,
                                                   nh_g + bo, nh_b + bo, ne_g + bo, ne_b + bo, tvec + bo,
                                                   plo_g + bo, plo_b + bo, x, x_bf, pe_b);
    if (l == L_LAYERS - 1) {
      k_gemm<2, true><<<dim3(E_EDGES / 128, 2), 256, 0, stream>>>(pe_b, WTplo + wo, E_EDGES, plo_b2 + bo,
                                                                  nullptr, nullptr, nullptr, e_bf, gn_sums);
    } else {
      k_gemm<2, false><<<dim3(E_EDGES / 128, 2), 256, 0, stream>>>(pe_b, WTplo + wo, E_EDGES, plo_b2 + bo,
                                                                   nullptr, nullptr, nullptr, e_bf, nullptr);
    }
  }

  k_gn_finalize<<<1, 64, 0, stream>>>(gn_sums, gstats);
  k_head<<<E_EDGES / 4, 256, 0, stream>>>(e_bf, gstats, gn_g, gn_b, out_w, out_b, out2);
}

// Round 9
// 872.665 us; speedup vs baseline: 1.0096x; 1.0096x over previous
//
#include <hip/hip_runtime.h>
#include <math.h>

#define V_NODES 3000
#define K_DEG 16
#define E_EDGES 48000
#define H 256
#define TE 128
#define L_LAYERS 12

typedef __attribute__((ext_vector_type(4))) float f32x4;
typedef __attribute__((ext_vector_type(8))) __bf16 bf16x8;
typedef __attribute__((ext_vector_type(4))) unsigned short u16x4;

__device__ __forceinline__ unsigned short f2bf(float f) {
  unsigned u = __float_as_uint(f);
  unsigned r = (u + 0x7fffu + ((u >> 16) & 1u)) >> 16;
  return (unsigned short)r;
}

__device__ __forceinline__ float bf2f(unsigned short u) {
  return __uint_as_float(((unsigned)u) << 16);
}

// fast sigmoid: 1/(1+2^(-x*log2e)) via v_exp_f32 + v_rcp_f32 (~1e-6 rel err)
__device__ __forceinline__ float fsig(float x) {
  return __builtin_amdgcn_rcpf(1.0f + __builtin_amdgcn_exp2f(-1.4426950408889634f * x));
}

__device__ __forceinline__ void gload16(const void* g, void* l) {
  __builtin_amdgcn_global_load_lds((const __attribute__((address_space(1))) void*)g,
                                   (__attribute__((address_space(3))) void*)l, 16, 0, 0);
}

// ---------------------------------------------------------------------------
// Weight prep: transpose 256x256 f32 [k][n] -> bf16 [n][k]; UVAB packed to
// [1024][256] per layer.
// ---------------------------------------------------------------------------
__global__ __launch_bounds__(256) void k_prep_w(const float* __restrict__ U_w, const float* __restrict__ V_w,
                                                const float* __restrict__ A_w, const float* __restrict__ B_w,
                                                const float* __restrict__ C_w, const float* __restrict__ plo_w,
                                                const float* __restrict__ edge_w,
                                                unsigned short* __restrict__ WT4, unsigned short* __restrict__ WTC,
                                                unsigned short* __restrict__ WTplo, unsigned short* __restrict__ WTedge) {
  int bid = blockIdx.x;
  const float* src;
  unsigned short* dst;
  int tt;
  if (bid < 768) {
    int l = bid >> 6;
    int rem = bid & 63;
    int mat = rem >> 4;
    tt = rem & 15;
    const float* srcs[4] = {U_w, V_w, A_w, B_w};
    src = srcs[mat] + (size_t)l * H * H;
    dst = WT4 + (size_t)l * 1024 * H + (size_t)mat * H * H;
  } else if (bid < 960) {
    int b2 = bid - 768;
    int l = b2 >> 4;
    tt = b2 & 15;
    src = C_w + (size_t)l * H * H;
    dst = WTC + (size_t)l * H * H;
  } else if (bid < 1152) {
    int b2 = bid - 960;
    int l = b2 >> 4;
    tt = b2 & 15;
    src = plo_w + (size_t)l * H * H;
    dst = WTplo + (size_t)l * H * H;
  } else {
    tt = bid - 1152;
    src = edge_w;
    dst = WTedge;
  }
  int k0 = (tt & 3) * 64, n0 = (tt >> 2) * 64;
  __shared__ float ts[64][65];
  int c = threadIdx.x & 63;
  int r0 = threadIdx.x >> 6;
  for (int rr = 0; rr < 64; rr += 4) {
    int r = rr + r0;
    ts[r][c] = src[(size_t)(k0 + r) * H + n0 + c];
  }
  __syncthreads();
  for (int nn = 0; nn < 64; nn += 4) {
    int n = nn + r0;
    dst[(size_t)(n0 + n) * H + k0 + c] = f2bf(ts[c][n]);
  }
}

__global__ __launch_bounds__(256) void k_prep_b(const float* __restrict__ U_b, const float* __restrict__ V_b,
                                                const float* __restrict__ A_b, const float* __restrict__ B_b,
                                                float* __restrict__ b4) {
  int l = blockIdx.x;
  int t = threadIdx.x;
  b4[l * 1024 + 0 + t] = U_b[l * H + t];
  b4[l * 1024 + 256 + t] = V_b[l * H + t];
  b4[l * 1024 + 512 + t] = A_b[l * H + t];
  b4[l * 1024 + 768 + t] = B_b[l * H + t];
}

// ---------------------------------------------------------------------------
// MFMA GEMM body (128x128 tile, 4 waves, BK=64) as device function so the
// dual kernel can run MODE 2 and MODE 0 blocks concurrently in one dispatch.
// MODE 0: node UVAB -> out_f32[m*1024+n] = acc + bias[n]
// MODE 2: edge plo  -> e_bf += acc + bias (bf16 storage); GN: fused stats
// MODE 3: edge embed-> acc + bias + mask_emb[mask[m]] -> e_bf
// ---------------------------------------------------------------------------
template <int MODE, bool GN>
__device__ __forceinline__ void gemm_body(char* lds,
                                          const unsigned short* __restrict__ A,
                                          const unsigned short* __restrict__ WT,
                                          int M,
                                          const float* __restrict__ bias,
                                          const int* __restrict__ maskp,
                                          const float* __restrict__ mask_emb,
                                          float* __restrict__ out_f32,
                                          unsigned short* __restrict__ out_bf16,
                                          double* __restrict__ gnp,
                                          int bx, int by) {
  const int t = threadIdx.x;
  const int m0 = bx * 128;
  const int nb = by * 128;
  const int lane = t & 63;
  const int wave = t >> 6;
  const int wr = wave >> 1, wc = wave & 1;
  const int lrow = lane & 15, lg = lane >> 4;

  char* Als = lds;
  char* Bls = lds + 16384;

  f32x4 acc[4][4];
#pragma unroll
  for (int i = 0; i < 4; ++i)
#pragma unroll
    for (int j = 0; j < 4; ++j) acc[i][j] = (f32x4)0.0f;

  for (int kt = 0; kt < 4; ++kt) {
    const int k0b = kt * 128;
#pragma unroll
    for (int i = 0; i < 4; ++i) {
      int o = i * 4096 + t * 16;
      int row = o >> 7;
      int cb = o & 127;
      int cbl = cb ^ ((row & 7) << 4);
      int rA = m0 + row;
      rA = rA < M ? rA : 0;
      gload16((const char*)A + (size_t)rA * 512 + k0b + cbl,
              Als + i * 4096 + (t & 192) * 16);
      gload16((const char*)WT + (size_t)(nb + row) * 512 + k0b + cbl,
              Bls + i * 4096 + (t & 192) * 16);
    }
    __syncthreads();
#pragma unroll
    for (int ks = 0; ks < 2; ++ks) {
      bf16x8 af[4], bfv[4];
#pragma unroll
      for (int mi = 0; mi < 4; ++mi) {
        int ra = wr * 64 + mi * 16 + lrow;
        int cba = (ks * 64 + lg * 16) ^ ((ra & 7) << 4);
        af[mi] = *(const bf16x8*)(Als + ra * 128 + cba);
        int rb = wc * 64 + mi * 16 + lrow;
        int cbb = (ks * 64 + lg * 16) ^ ((rb & 7) << 4);
        bfv[mi] = *(const bf16x8*)(Bls + rb * 128 + cbb);
      }
#pragma unroll
      for (int mi = 0; mi < 4; ++mi)
#pragma unroll
        for (int ni = 0; ni < 4; ++ni)
          acc[mi][ni] = __builtin_amdgcn_mfma_f32_16x16x32_bf16(af[mi], bfv[ni], acc[mi][ni], 0, 0, 0);
    }
    __syncthreads();
  }

  double ps[4] = {0, 0, 0, 0}, pq[4] = {0, 0, 0, 0};
#pragma unroll
  for (int mi = 0; mi < 4; ++mi) {
#pragma unroll
    for (int r = 0; r < 4; ++r) {
      int m = m0 + wr * 64 + mi * 16 + lg * 4 + r;
      if (MODE == 0 && m >= M) continue;
      int mk = 0;
      if constexpr (MODE == 3) { mk = maskp[m]; }
#pragma unroll
      for (int ni = 0; ni < 4; ++ni) {
        int n = nb + wc * 64 + ni * 16 + lrow;
        float v = acc[mi][ni][r] + bias[n];
        if constexpr (MODE == 0) {
          out_f32[(size_t)m * 1024 + n] = v;
        } else if constexpr (MODE == 2) {
          float eo = bf2f(out_bf16[(size_t)m * 256 + n]);
          unsigned short nb16 = f2bf(eo + v);
          out_bf16[(size_t)m * 256 + n] = nb16;
          if constexpr (GN) {
            float rv = bf2f(nb16);
            ps[ni] += (double)rv;
            pq[ni] += (double)rv * (double)rv;
          }
        } else {
          v += mask_emb[mk * 256 + n];
          out_bf16[(size_t)m * 256 + n] = f2bf(v);
        }
      }
    }
  }

  if constexpr (GN) {
    __syncthreads();
    double* redS = (double*)lds;           // [128][8] f64 = 8KB
    double* redQ = (double*)(lds + 8192);  // 8KB
    int slot = wr * 4 + lg;
#pragma unroll
    for (int ni = 0; ni < 4; ++ni) {
      int cn = wc * 64 + ni * 16 + lrow;
      redS[cn * 8 + slot] = ps[ni];
      redQ[cn * 8 + slot] = pq[ni];
    }
    __syncthreads();
    if (t < 128) {
      double s = 0, q = 0;
#pragma unroll
      for (int k = 0; k < 8; ++k) { s += redS[t * 8 + k]; q += redQ[t * 8 + k]; }
      atomicAdd(&gnp[nb + t], s);
      atomicAdd(&gnp[H + nb + t], q);
    }
  }
}

template <int MODE, bool GN>
__global__ __launch_bounds__(256) void k_gemm(const unsigned short* __restrict__ A,
                                              const unsigned short* __restrict__ WT,
                                              int M,
                                              const float* __restrict__ bias,
                                              const int* __restrict__ maskp,
                                              const float* __restrict__ mask_emb,
                                              float* __restrict__ out_f32,
                                              unsigned short* __restrict__ out_bf16,
                                              double* __restrict__ gnp) {
  __shared__ __align__(16) char lds[32768];
  gemm_body<MODE, GN>(lds, A, WT, M, bias, maskp, mask_emb, out_f32, out_bf16, gnp,
                      blockIdx.x, blockIdx.y);
}

// Dual dispatch: blocks [0,750) = MODE 2 plo-GEMM of layer l;
// blocks [750,942) = MODE 0 UVAB-GEMM of layer l+1. Independent outputs.
__global__ __launch_bounds__(256) void k_gemm_dual(const unsigned short* __restrict__ pe_b,
                                                   const unsigned short* __restrict__ WTplo_l,
                                                   const float* __restrict__ plo_b2_l,
                                                   unsigned short* __restrict__ e_bf,
                                                   const unsigned short* __restrict__ x_bf,
                                                   const unsigned short* __restrict__ WT4_n,
                                                   const float* __restrict__ b4_n,
                                                   float* __restrict__ XW) {
  __shared__ __align__(16) char lds[32768];
  int b = blockIdx.x;
  if (b < 750) {
    gemm_body<2, false>(lds, pe_b, WTplo_l, E_EDGES, plo_b2_l, nullptr, nullptr,
                        nullptr, e_bf, nullptr, b % 375, b / 375);
  } else {
    int b2 = b - 750;
    gemm_body<0, false>(lds, x_bf, WT4_n, V_NODES, b4_n, nullptr, nullptr,
                        XW, nullptr, nullptr, b2 % 24, b2 / 24);
  }
}

// ---------------------------------------------------------------------------
// Fused layer-edge kernel v3: BM=32 (2 nodes), BN=256, 8 waves (512 thr).
// LDS = max(A 4K + B 32K, enew 32x256 f32) = 36KB -> 4 blocks/CU.
// E0: acc + Cb + Ah[col] + Bh[row] -> enew (XOR-swizzled f32)
// E1: node update (waves 0-1, one node each)
// E2: double-LN+silu -> bout bf16 (all 8 waves, 4 rows each)
// ---------------------------------------------------------------------------
__global__ __launch_bounds__(512, 8) void k_layer_edge(const unsigned short* __restrict__ A,
                                                       const unsigned short* __restrict__ WT,
                                                       const float* __restrict__ Cb,
                                                       const int* __restrict__ ei_col,
                                                       const float* __restrict__ XW,
                                                       const float* __restrict__ nhg, const float* __restrict__ nhb,
                                                       const float* __restrict__ neg_, const float* __restrict__ neb_,
                                                       const float* __restrict__ tvec_l,
                                                       const float* __restrict__ pg_, const float* __restrict__ pb_,
                                                       float* __restrict__ x, unsigned short* __restrict__ xb,
                                                       unsigned short* __restrict__ bout) {
  const int t = threadIdx.x;
  const int m0 = blockIdx.x * 32;
  const int lane = t & 63;
  const int wave = t >> 6;      // 8 col-groups of 32 cols each
  const int wc = wave;
  const int lrow = lane & 15, lg = lane >> 4;
  const int c0 = lane * 4;

  __shared__ __align__(16) char lds[36864];
  char* Als = lds;            // [32][128B] swizzled (GEMM phase)
  char* Bls = lds + 4096;     // [256][128B] swizzled (GEMM phase)
  float* enew = (float*)lds;  // [32][256] f32 swizzled (epilogue)

  f32x4 acc[2][2];
#pragma unroll
  for (int i = 0; i < 2; ++i)
#pragma unroll
    for (int j = 0; j < 2; ++j) acc[i][j] = (f32x4)0.0f;

  const int wave_off = wave * 1024;
  for (int kt = 0; kt < 4; ++kt) {
    const int k0b = kt * 128;
    if (t < 256) {  // A: 32 rows x 128B = 4KB
      int o = t * 16;
      int row = o >> 7;
      int cbl = (o & 127) ^ ((row & 7) << 4);
      gload16((const char*)A + (size_t)(m0 + row) * 512 + k0b + cbl, Als + wave_off);
    }
#pragma unroll
    for (int c = 0; c < 4; ++c) {  // B: 256 rows x 128B = 32KB
      int o = c * 8192 + t * 16;
      int row = o >> 7;
      int cbl = (o & 127) ^ ((row & 7) << 4);
      gload16((const char*)WT + (size_t)row * 512 + k0b + cbl, Bls + c * 8192 + wave_off);
    }
    __syncthreads();
#pragma unroll
    for (int ks = 0; ks < 2; ++ks) {
      bf16x8 af[2], bfv[2];
#pragma unroll
      for (int mi = 0; mi < 2; ++mi) {
        int ra = mi * 16 + lrow;
        af[mi] = *(const bf16x8*)(Als + ra * 128 + ((ks * 64 + lg * 16) ^ ((ra & 7) << 4)));
      }
#pragma unroll
      for (int ni = 0; ni < 2; ++ni) {
        int rb = wc * 32 + ni * 16 + lrow;
        bfv[ni] = *(const bf16x8*)(Bls + rb * 128 + ((ks * 64 + lg * 16) ^ ((rb & 7) << 4)));
      }
#pragma unroll
      for (int mi = 0; mi < 2; ++mi)
#pragma unroll
        for (int ni = 0; ni < 2; ++ni)
          acc[mi][ni] = __builtin_amdgcn_mfma_f32_16x16x32_bf16(af[mi], bfv[ni], acc[mi][ni], 0, 0, 0);
    }
    __syncthreads();
  }

  // ---- E0: acc + Cb + Ah[col] + Bh[node] -> enew (swizzled f32) ----
  {
    float bs[2];
#pragma unroll
    for (int ni = 0; ni < 2; ++ni) bs[ni] = Cb[wc * 32 + ni * 16 + lrow];
#pragma unroll
    for (int mi = 0; mi < 2; ++mi) {
#pragma unroll
      for (int r = 0; r < 4; ++r) {
        int ml = mi * 16 + lg * 4 + r;
        int m = m0 + ml;
        int cv = ei_col[m];
        const float* AhR = XW + (size_t)cv * 1024 + 512;
        const float* BhR = XW + (size_t)(m >> 4) * 1024 + 768;
        int sw = (ml & 15) << 2;
#pragma unroll
        for (int ni = 0; ni < 2; ++ni) {
          int n = wc * 32 + ni * 16 + lrow;
          enew[ml * 256 + (n ^ sw)] = acc[mi][ni][r] + bs[ni] + AhR[n] + BhR[n];
        }
      }
    }
  }
  __syncthreads();

  // ---- E1: node update (waves 0-1, one node each) ----
  if (wave < 2) {
    int v = (m0 >> 4) + wave;
    f32x4 agg = (f32x4)0.0f;
#pragma unroll 4
    for (int k = 0; k < K_DEG; ++k) {
      int row = wave * 16 + k;
      int cv = ei_col[m0 + row];
      f32x4 en = *(const f32x4*)&enew[row * 256 + (c0 ^ ((row & 15) << 2))];
      f32x4 vh = *(const f32x4*)&XW[(size_t)cv * 1024 + 256 + c0];
#pragma unroll
      for (int i = 0; i < 4; ++i) agg[i] += vh[i] * fsig(en[i]);
    }
    f32x4 s4 = *(const f32x4*)&XW[(size_t)v * 1024 + c0];  // Uh
    s4 += agg;
    float s = s4[0] + s4[1] + s4[2] + s4[3];
    float sq = s4[0] * s4[0] + s4[1] * s4[1] + s4[2] * s4[2] + s4[3] * s4[3];
#pragma unroll
    for (int st = 1; st < 64; st <<= 1) { s += __shfl_xor(s, st); sq += __shfl_xor(sq, st); }
    float mean = s * (1.0f / H);
    float inv = rsqrtf(sq * (1.0f / H) - mean * mean + 1e-5f);
    f32x4 g = *(const f32x4*)&nhg[c0];
    f32x4 bb = *(const f32x4*)&nhb[c0];
    f32x4 xo = *(const f32x4*)&x[(size_t)v * H + c0];
    u16x4 ov;
#pragma unroll
    for (int i = 0; i < 4; ++i) {
      float h = fmaxf((s4[i] - mean) * inv * g[i] + bb[i], 0.0f);
      xo[i] += h;
      ov[i] = f2bf(xo[i]);
    }
    *(f32x4*)&x[(size_t)v * H + c0] = xo;
    *(u16x4*)&xb[(size_t)v * H + c0] = ov;
  }

  // ---- E2: double-LN + silu chain -> bout bf16 (4 rows per wave) ----
  {
    f32x4 g1 = *(const f32x4*)&neg_[c0];
    f32x4 b1 = *(const f32x4*)&neb_[c0];
    f32x4 tv = *(const f32x4*)&tvec_l[c0];
    f32x4 g2 = *(const f32x4*)&pg_[c0];
    f32x4 b2 = *(const f32x4*)&pb_[c0];
#pragma unroll
    for (int k = 0; k < 4; ++k) {
      int row = wave + 8 * k;
      f32x4 vv = *(const f32x4*)&enew[row * 256 + (c0 ^ ((row & 15) << 2))];
      float s = vv[0] + vv[1] + vv[2] + vv[3];
      float sq = vv[0] * vv[0] + vv[1] * vv[1] + vv[2] * vv[2] + vv[3] * vv[3];
#pragma unroll
      for (int st = 1; st < 64; st <<= 1) { s += __shfl_xor(s, st); sq += __shfl_xor(sq, st); }
      float mean = s * (1.0f / H);
      float inv = rsqrtf(sq * (1.0f / H) - mean * mean + 1e-5f);
      f32x4 a;
#pragma unroll
      for (int i = 0; i < 4; ++i) a[i] = fmaxf((vv[i] - mean) * inv * g1[i] + b1[i], 0.0f) + tv[i];
      s = a[0] + a[1] + a[2] + a[3];
      sq = a[0] * a[0] + a[1] * a[1] + a[2] * a[2] + a[3] * a[3];
#pragma unroll
      for (int st = 1; st < 64; st <<= 1) { s += __shfl_xor(s, st); sq += __shfl_xor(sq, st); }
      mean = s * (1.0f / H);
      inv = rsqrtf(sq * (1.0f / H) - mean * mean + 1e-5f);
      u16x4 ov;
#pragma unroll
      for (int i = 0; i < 4; ++i) {
        float n = (a[i] - mean) * inv * g2[i] + b2[i];
        ov[i] = f2bf(n * fsig(n));
      }
      *(u16x4*)&bout[(size_t)(m0 + row) * H + c0] = ov;
    }
  }
}

// ---------------------------------------------------------------------------
// Node positional embedding + node_w matmul
// ---------------------------------------------------------------------------
__global__ __launch_bounds__(256) void k_node_embed(const float* __restrict__ coords,
                                                    const float* __restrict__ W,
                                                    const float* __restrict__ b,
                                                    float* __restrict__ x,
                                                    unsigned short* __restrict__ xb) {
  int v = blockIdx.x;
  int j = threadIdx.x;
  __shared__ float4 pe4[H / 4];
  float cy = coords[v * 2 + 0] * 6.283185307179586f;
  float cx = coords[v * 2 + 1] * 6.283185307179586f;
  int idx = j & 127;
  float coord = (j < 128) ? cy : cx;
  float dim_t = powf(10000.0f, (2.0f * (float)(idx >> 1)) / 128.0f);
  float val = coord / dim_t;
  ((float*)pe4)[j] = (idx & 1) ? cosf(val) : sinf(val);
  __syncthreads();
  float acc = b[j];
  for (int k4 = 0; k4 < H / 4; ++k4) {
    float4 p = pe4[k4];
    int k = 4 * k4;
    acc += p.x * W[(k + 0) * H + j] + p.y * W[(k + 1) * H + j] +
           p.z * W[(k + 2) * H + j] + p.w * W[(k + 3) * H + j];
  }
  x[(size_t)v * H + j] = acc;
  xb[(size_t)v * H + j] = f2bf(acc);
}

// ---------------------------------------------------------------------------
// Edge scalar sine embedding -> pe bf16
// ---------------------------------------------------------------------------
__global__ __launch_bounds__(256) void k_pe(const float* __restrict__ e_vals, unsigned short* __restrict__ pe) {
  int eid = blockIdx.x * 4 + (threadIdx.x >> 6);
  int lane = threadIdx.x & 63;
  int c0 = lane * 4;
  float val = e_vals[eid];
  const float lg = 13.287712379549449f / 256.0f;
  u16x4 ov;
#pragma unroll
  for (int i = 0; i < 4; ++i) {
    int c = c0 + i;
    float invd = exp2f(-(float)(c & ~1) * lg);
    float arg = val * invd;
    float s = (c & 1) ? cosf(arg) : sinf(arg);
    ov[i] = f2bf(s);
  }
  *(u16x4*)&pe[(size_t)eid * H + c0] = ov;
}

// ---------------------------------------------------------------------------
// Timestep embedding MLP + per-layer conditioning
// ---------------------------------------------------------------------------
__global__ __launch_bounds__(256) void k_temb(const int* __restrict__ t,
                                              const float* __restrict__ te1_w, const float* __restrict__ te1_b,
                                              const float* __restrict__ te2_w, const float* __restrict__ te2_b,
                                              float* __restrict__ temb_out) {
  __shared__ float emb[H];
  __shared__ float h1[TE];
  int j = threadIdx.x;
  float tv = (float)t[0];
  {
    int i = j & 127;
    float f = expf(-logf(10000.0f) * (float)i / 128.0f);
    float arg = tv * f;
    emb[j] = (j < 128) ? cosf(arg) : sinf(arg);
  }
  __syncthreads();
  if (j < TE) {
    float acc = te1_b[j];
    for (int k = 0; k < H; ++k) acc += emb[k] * te1_w[k * TE + j];
    h1[j] = fmaxf(acc, 0.0f);
  }
  __syncthreads();
  if (j < TE) {
    float acc = te2_b[j];
    for (int k = 0; k < TE; ++k) acc += h1[k] * te2_w[k * TE + j];
    temb_out[j] = acc;
  }
}

__global__ __launch_bounds__(256) void k_tvec(const float* __restrict__ temb,
                                              const float* __restrict__ tl_w, const float* __restrict__ tl_b,
                                              float* __restrict__ tvec) {
  int l = blockIdx.x;
  int j = threadIdx.x;
  __shared__ float rt[TE];
  if (j < TE) rt[j] = fmaxf(temb[j], 0.0f);
  __syncthreads();
  float acc = tl_b[l * H + j];
  for (int k = 0; k < TE; ++k) acc += rt[k] * tl_w[(size_t)(l * TE + k) * H + j];
  tvec[l * H + j] = acc;
}

__global__ void k_gn_finalize(const double* __restrict__ sums, float* __restrict__ gstats) {
  int g = threadIdx.x;
  if (g < 32) {
    double s = 0.0, sq = 0.0;
    for (int c = g * 8; c < g * 8 + 8; ++c) {
      s += sums[c];
      sq += sums[H + c];
    }
    double n = 8.0 * (double)E_EDGES;
    double mean = s / n;
    double var = sq / n - mean * mean;
    gstats[g] = (float)mean;
    gstats[32 + g] = (float)(1.0 / sqrt(var + 1e-5));
  }
}

__global__ __launch_bounds__(256) void k_head(const unsigned short* __restrict__ e_bf,
                                              const float* __restrict__ gstats,
                                              const float* __restrict__ gn_g, const float* __restrict__ gn_b,
                                              const float* __restrict__ out_w, const float* __restrict__ out_b,
                                              float* __restrict__ out) {
  int wv = threadIdx.x >> 6;
  int lane = threadIdx.x & 63;
  int eid = blockIdx.x * 4 + wv;
  int c0 = lane * 4;
  u16x4 ev = *(const u16x4*)&e_bf[(size_t)eid * H + c0];
  float a0 = 0.0f, a1 = 0.0f;
#pragma unroll
  for (int i = 0; i < 4; ++i) {
    int c = c0 + i;
    int g = c >> 3;
    float v = (bf2f(ev[i]) - gstats[g]) * gstats[32 + g] * gn_g[c] + gn_b[c];
    v = fmaxf(v, 0.0f);
    a0 += v * out_w[c * 2 + 0];
    a1 += v * out_w[c * 2 + 1];
  }
  for (int s = 32; s > 0; s >>= 1) {
    a0 += __shfl_down(a0, s);
    a1 += __shfl_down(a1, s);
  }
  if (lane == 0) {
    out[(size_t)eid * 2 + 0] = a0 + out_b[0];
    out[(size_t)eid * 2 + 1] = a1 + out_b[1];
  }
}

// ---------------------------------------------------------------------------
extern "C" void kernel_launch(void* const* d_in, const int* in_sizes, int n_in,
                              void* d_out, int out_size, void* d_ws, size_t ws_size,
                              hipStream_t stream) {
  const float* nodes_feature = (const float*)d_in[0];
  const float* e_vals = (const float*)d_in[1];
  const int* mask = (const int*)d_in[2];
  const int* t = (const int*)d_in[3];
  const int* edge_index = (const int*)d_in[4];
  const float* node_w = (const float*)d_in[5];
  const float* node_b = (const float*)d_in[6];
  const float* edge_w = (const float*)d_in[7];
  const float* edge_b = (const float*)d_in[8];
  const float* te1_w = (const float*)d_in[9];
  const float* te1_b = (const float*)d_in[10];
  const float* te2_w = (const float*)d_in[11];
  const float* te2_b = (const float*)d_in[12];
  const float* U_w = (const float*)d_in[13];
  const float* U_b = (const float*)d_in[14];
  const float* V_w = (const float*)d_in[15];
  const float* V_b = (const float*)d_in[16];
  const float* A_w = (const float*)d_in[17];
  const float* A_b = (const float*)d_in[18];
  const float* B_w = (const float*)d_in[19];
  const float* B_b = (const float*)d_in[20];
  const float* C_w = (const float*)d_in[21];
  const float* C_b = (const float*)d_in[22];
  const float* nh_g = (const float*)d_in[23];
  const float* nh_b = (const float*)d_in[24];
  const float* ne_g = (const float*)d_in[25];
  const float* ne_b = (const float*)d_in[26];
  const float* tl_w = (const float*)d_in[27];
  const float* tl_b = (const float*)d_in[28];
  const float* plo_g = (const float*)d_in[29];
  const float* plo_b = (const float*)d_in[30];
  const float* plo_w = (const float*)d_in[31];
  const float* plo_b2 = (const float*)d_in[32];
  const float* gn_g = (const float*)d_in[33];
  const float* gn_b = (const float*)d_in[34];
  const float* out_w = (const float*)d_in[35];
  const float* out_b = (const float*)d_in[36];
  const float* mask_emb = (const float*)d_in[37];

  char* wsb = (char*)d_ws;
  size_t off = 0;
  auto alloc = [&](size_t bytes) -> void* {
    void* p = wsb + off;
    off += (bytes + 255) & ~(size_t)255;
    return p;
  };
  double* gn_sums = (double*)alloc(512 * sizeof(double));
  float* XW = (float*)alloc((size_t)V_NODES * 1024 * 4);
  unsigned short* e_bf = (unsigned short*)alloc((size_t)E_EDGES * H * 2);
  unsigned short* pe_b = (unsigned short*)alloc((size_t)E_EDGES * H * 2);
  unsigned short* x_bf = (unsigned short*)alloc((size_t)V_NODES * H * 2);
  unsigned short* WT4 = (unsigned short*)alloc((size_t)L_LAYERS * 1024 * H * 2);
  unsigned short* WTC = (unsigned short*)alloc((size_t)L_LAYERS * H * H * 2);
  unsigned short* WTplo = (unsigned short*)alloc((size_t)L_LAYERS * H * H * 2);
  unsigned short* WTedge = (unsigned short*)alloc((size_t)H * H * 2);
  float* b4 = (float*)alloc((size_t)L_LAYERS * 1024 * 4);
  float* temb = (float*)alloc(TE * 4);
  float* tvec = (float*)alloc((size_t)L_LAYERS * H * 4);
  float* gstats = (float*)alloc(64 * 4);

  const int* ei_col = edge_index + E_EDGES;

  float* x = (float*)d_out;
  float* out2 = (float*)d_out + (size_t)V_NODES * H;

  k_prep_w<<<1168, 256, 0, stream>>>(U_w, V_w, A_w, B_w, C_w, plo_w, edge_w, WT4, WTC, WTplo, WTedge);
  k_prep_b<<<L_LAYERS, 256, 0, stream>>>(U_b, V_b, A_b, B_b, b4);
  k_node_embed<<<V_NODES, 256, 0, stream>>>(nodes_feature, node_w, node_b, x, x_bf);
  k_pe<<<E_EDGES / 4, 256, 0, stream>>>(e_vals, pe_b);
  k_temb<<<1, 256, 0, stream>>>(t, te1_w, te1_b, te2_w, te2_b, temb);
  k_tvec<<<L_LAYERS, 256, 0, stream>>>(temb, tl_w, tl_b, tvec);
  k_gemm<3, false><<<dim3(E_EDGES / 128, 2), 256, 0, stream>>>(pe_b, WTedge, E_EDGES, edge_b, mask, mask_emb,
                                                               nullptr, e_bf, nullptr);
  hipMemsetAsync(gn_sums, 0, 512 * sizeof(double), stream);

  // Layer-0 node GEMM (standalone), then per layer: fused edge kernel followed
  // by a dual dispatch running {plo-GEMM(l), UVAB-GEMM(l+1)} concurrently.
  k_gemm<0, false><<<dim3(24, 8), 256, 0, stream>>>(x_bf, WT4, V_NODES, b4,
                                                    nullptr, nullptr, XW, nullptr, nullptr);
  for (int l = 0; l < L_LAYERS; ++l) {
    size_t wo = (size_t)l * H * H;
    size_t bo = (size_t)l * H;
    k_layer_edge<<<E_EDGES / 32, 512, 0, stream>>>(e_bf, WTC + wo, C_b + bo, ei_col, XW,
                                                   nh_g + bo, nh_b + bo, ne_g + bo, ne_b + bo, tvec + bo,
                                                   plo_g + bo, plo_b + bo, x, x_bf, pe_b);
    if (l < L_LAYERS - 1) {
      k_gemm_dual<<<942, 256, 0, stream>>>(pe_b, WTplo + wo, plo_b2 + bo, e_bf,
                                           x_bf, WT4 + (size_t)(l + 1) * 1024 * H, b4 + (l + 1) * 1024, XW);
    } else {
      k_gemm<2, true><<<dim3(E_EDGES / 128, 2), 256, 0, stream>>>(pe_b, WTplo + wo, E_EDGES, plo_b2 + bo,
                                                                  nullptr, nullptr, nullptr, e_bf, gn_sums);
    }
  }

  k_gn_finalize<<<1, 64, 0, stream>>>(gn_sums, gstats);
  k_head<<<E_EDGES / 4, 256, 0, stream>>>(e_bf, gstats, gn_g, gn_b, out_w, out_b, out2);
}

// Round 10
// 792.719 us; speedup vs baseline: 1.1115x; 1.1009x over previous
//
#include <hip/hip_runtime.h>
#include <math.h>

#define V_NODES 3000
#define K_DEG 16
#define E_EDGES 48000
#define H 256
#define TE 128
#define L_LAYERS 12

typedef __attribute__((ext_vector_type(4))) float f32x4;
typedef __attribute__((ext_vector_type(8))) __bf16 bf16x8;
typedef __attribute__((ext_vector_type(4))) unsigned short u16x4;

__device__ __forceinline__ unsigned short f2bf(float f) {
  unsigned u = __float_as_uint(f);
  unsigned r = (u + 0x7fffu + ((u >> 16) & 1u)) >> 16;
  return (unsigned short)r;
}

__device__ __forceinline__ float bf2f(unsigned short u) {
  return __uint_as_float(((unsigned)u) << 16);
}

// fast sigmoid: 1/(1+2^(-x*log2e)) via v_exp_f32 + v_rcp_f32 (~1e-6 rel err)
__device__ __forceinline__ float fsig(float x) {
  return __builtin_amdgcn_rcpf(1.0f + __builtin_amdgcn_exp2f(-1.4426950408889634f * x));
}

__device__ __forceinline__ void gload16(const void* g, void* l) {
  __builtin_amdgcn_global_load_lds((const __attribute__((address_space(1))) void*)g,
                                   (__attribute__((address_space(3))) void*)l, 16, 0, 0);
}

// ---------------------------------------------------------------------------
// Preamble bodies (merged into one uber-dispatch k_pre):
//  [0,1168)      prep_w : transpose f32 [k][n] -> bf16 [n][k] (UVAB/C/plo/edge)
//  [1168,1180)   prep_b : pack UVAB biases
//  [1180,4180)   node_embed : pos-embed + node_w matmul -> x f32 + x_bf
//  [4180,16180)  pe : edge scalar sine embedding -> pe bf16
//  [16180,16192) temb+tvec : per-layer conditioning (temb recomputed per block)
// All families independent; block-uniform branch.
// ---------------------------------------------------------------------------
__device__ void prep_w_body(char* ldsraw, int bid,
                            const float* __restrict__ U_w, const float* __restrict__ V_w,
                            const float* __restrict__ A_w, const float* __restrict__ B_w,
                            const float* __restrict__ C_w, const float* __restrict__ plo_w,
                            const float* __restrict__ edge_w,
                            unsigned short* __restrict__ WT4, unsigned short* __restrict__ WTC,
                            unsigned short* __restrict__ WTplo, unsigned short* __restrict__ WTedge) {
  const float* src;
  unsigned short* dst;
  int tt;
  if (bid < 768) {
    int l = bid >> 6;
    int rem = bid & 63;
    int mat = rem >> 4;
    tt = rem & 15;
    const float* srcs[4] = {U_w, V_w, A_w, B_w};
    src = srcs[mat] + (size_t)l * H * H;
    dst = WT4 + (size_t)l * 1024 * H + (size_t)mat * H * H;
  } else if (bid < 960) {
    int b2 = bid - 768;
    int l = b2 >> 4;
    tt = b2 & 15;
    src = C_w + (size_t)l * H * H;
    dst = WTC + (size_t)l * H * H;
  } else if (bid < 1152) {
    int b2 = bid - 960;
    int l = b2 >> 4;
    tt = b2 & 15;
    src = plo_w + (size_t)l * H * H;
    dst = WTplo + (size_t)l * H * H;
  } else {
    tt = bid - 1152;
    src = edge_w;
    dst = WTedge;
  }
  int k0 = (tt & 3) * 64, n0 = (tt >> 2) * 64;
  float (*ts)[65] = (float(*)[65])ldsraw;
  int c = threadIdx.x & 63;
  int r0 = threadIdx.x >> 6;
  for (int rr = 0; rr < 64; rr += 4) {
    int r = rr + r0;
    ts[r][c] = src[(size_t)(k0 + r) * H + n0 + c];
  }
  __syncthreads();
  for (int nn = 0; nn < 64; nn += 4) {
    int n = nn + r0;
    dst[(size_t)(n0 + n) * H + k0 + c] = f2bf(ts[c][n]);
  }
}

__device__ void prep_b_body(int l,
                            const float* __restrict__ U_b, const float* __restrict__ V_b,
                            const float* __restrict__ A_b, const float* __restrict__ B_b,
                            float* __restrict__ b4) {
  int t = threadIdx.x;
  b4[l * 1024 + 0 + t] = U_b[l * H + t];
  b4[l * 1024 + 256 + t] = V_b[l * H + t];
  b4[l * 1024 + 512 + t] = A_b[l * H + t];
  b4[l * 1024 + 768 + t] = B_b[l * H + t];
}

__device__ void node_embed_body(char* ldsraw, int v,
                                const float* __restrict__ coords,
                                const float* __restrict__ W,
                                const float* __restrict__ b,
                                float* __restrict__ x,
                                unsigned short* __restrict__ xb) {
  int j = threadIdx.x;
  float4* pe4 = (float4*)ldsraw;
  float cy = coords[v * 2 + 0] * 6.283185307179586f;
  float cx = coords[v * 2 + 1] * 6.283185307179586f;
  int idx = j & 127;
  float coord = (j < 128) ? cy : cx;
  float dim_t = powf(10000.0f, (2.0f * (float)(idx >> 1)) / 128.0f);
  float val = coord / dim_t;
  ((float*)pe4)[j] = (idx & 1) ? cosf(val) : sinf(val);
  __syncthreads();
  float acc = b[j];
  for (int k4 = 0; k4 < H / 4; ++k4) {
    float4 p = pe4[k4];
    int k = 4 * k4;
    acc += p.x * W[(k + 0) * H + j] + p.y * W[(k + 1) * H + j] +
           p.z * W[(k + 2) * H + j] + p.w * W[(k + 3) * H + j];
  }
  x[(size_t)v * H + j] = acc;
  xb[(size_t)v * H + j] = f2bf(acc);
}

__device__ void pe_body(int b, const float* __restrict__ e_vals, unsigned short* __restrict__ pe) {
  int eid = b * 4 + (threadIdx.x >> 6);
  int lane = threadIdx.x & 63;
  int c0 = lane * 4;
  float val = e_vals[eid];
  const float lg = 13.287712379549449f / 256.0f;
  u16x4 ov;
#pragma unroll
  for (int i = 0; i < 4; ++i) {
    int c = c0 + i;
    float invd = exp2f(-(float)(c & ~1) * lg);
    float arg = val * invd;
    float s = (c & 1) ? cosf(arg) : sinf(arg);
    ov[i] = f2bf(s);
  }
  *(u16x4*)&pe[(size_t)eid * H + c0] = ov;
}

__device__ void temb_tvec_body(char* ldsraw, int l,
                               const int* __restrict__ t,
                               const float* __restrict__ te1_w, const float* __restrict__ te1_b,
                               const float* __restrict__ te2_w, const float* __restrict__ te2_b,
                               const float* __restrict__ tl_w, const float* __restrict__ tl_b,
                               float* __restrict__ tvec) {
  float* emb = (float*)ldsraw;            // [256]
  float* h1 = (float*)(ldsraw + 1024);    // [128]
  float* rt = (float*)(ldsraw + 1536);    // [128]
  int j = threadIdx.x;
  float tv = (float)t[0];
  {
    int i = j & 127;
    float f = expf(-logf(10000.0f) * (float)i / 128.0f);
    float arg = tv * f;
    emb[j] = (j < 128) ? cosf(arg) : sinf(arg);
  }
  __syncthreads();
  if (j < TE) {
    float acc = te1_b[j];
    for (int k = 0; k < H; ++k) acc += emb[k] * te1_w[k * TE + j];
    h1[j] = fmaxf(acc, 0.0f);
  }
  __syncthreads();
  if (j < TE) {
    float acc = te2_b[j];
    for (int k = 0; k < TE; ++k) acc += h1[k] * te2_w[k * TE + j];
    rt[j] = fmaxf(acc, 0.0f);  // relu(temb), identical to temb->tvec chain
  }
  __syncthreads();
  float acc = tl_b[l * H + j];
  for (int k = 0; k < TE; ++k) acc += rt[k] * tl_w[(size_t)(l * TE + k) * H + j];
  tvec[l * H + j] = acc;
}

__global__ __launch_bounds__(256) void k_pre(const float* __restrict__ U_w, const float* __restrict__ V_w,
                                             const float* __restrict__ A_w, const float* __restrict__ B_w,
                                             const float* __restrict__ C_w, const float* __restrict__ plo_w,
                                             const float* __restrict__ edge_w,
                                             unsigned short* __restrict__ WT4, unsigned short* __restrict__ WTC,
                                             unsigned short* __restrict__ WTplo, unsigned short* __restrict__ WTedge,
                                             const float* __restrict__ U_b, const float* __restrict__ V_b,
                                             const float* __restrict__ A_b, const float* __restrict__ B_b,
                                             float* __restrict__ b4,
                                             const float* __restrict__ coords,
                                             const float* __restrict__ node_w, const float* __restrict__ node_b,
                                             float* __restrict__ x, unsigned short* __restrict__ xb,
                                             const float* __restrict__ e_vals, unsigned short* __restrict__ pe,
                                             const int* __restrict__ t,
                                             const float* __restrict__ te1_w, const float* __restrict__ te1_b,
                                             const float* __restrict__ te2_w, const float* __restrict__ te2_b,
                                             const float* __restrict__ tl_w, const float* __restrict__ tl_b,
                                             float* __restrict__ tvec) {
  __shared__ __align__(16) char lds[16896];
  int b = blockIdx.x;
  if (b < 1168) {
    prep_w_body(lds, b, U_w, V_w, A_w, B_w, C_w, plo_w, edge_w, WT4, WTC, WTplo, WTedge);
  } else if (b < 1180) {
    prep_b_body(b - 1168, U_b, V_b, A_b, B_b, b4);
  } else if (b < 4180) {
    node_embed_body(lds, b - 1180, coords, node_w, node_b, x, xb);
  } else if (b < 16180) {
    pe_body(b - 4180, e_vals, pe);
  } else {
    temb_tvec_body(lds, b - 16180, t, te1_w, te1_b, te2_w, te2_b, tl_w, tl_b, tvec);
  }
}

// ---------------------------------------------------------------------------
// Plain MFMA GEMM (128x128 tile, 4 waves, BK=64).
// MODE 0: node UVAB -> out_f32[m*1024+n] = acc + bias[n]
// MODE 2: edge plo  -> e_bf += acc + bias (bf16 storage); GN: fused stats
// MODE 3: edge embed-> acc + bias + mask_emb[mask[m]] -> e_bf
// ---------------------------------------------------------------------------
template <int MODE, bool GN>
__global__ __launch_bounds__(256) void k_gemm(const unsigned short* __restrict__ A,
                                              const unsigned short* __restrict__ WT,
                                              int M,
                                              const float* __restrict__ bias,
                                              const int* __restrict__ maskp,
                                              const float* __restrict__ mask_emb,
                                              float* __restrict__ out_f32,
                                              unsigned short* __restrict__ out_bf16,
                                              double* __restrict__ gnp) {
  const int t = threadIdx.x;
  const int m0 = blockIdx.x * 128;
  const int nb = blockIdx.y * 128;
  const int lane = t & 63;
  const int wave = t >> 6;
  const int wr = wave >> 1, wc = wave & 1;
  const int lrow = lane & 15, lg = lane >> 4;

  __shared__ __align__(16) char lds[32768];
  char* Als = lds;
  char* Bls = lds + 16384;

  f32x4 acc[4][4];
#pragma unroll
  for (int i = 0; i < 4; ++i)
#pragma unroll
    for (int j = 0; j < 4; ++j) acc[i][j] = (f32x4)0.0f;

  for (int kt = 0; kt < 4; ++kt) {
    const int k0b = kt * 128;
#pragma unroll
    for (int i = 0; i < 4; ++i) {
      int o = i * 4096 + t * 16;
      int row = o >> 7;
      int cb = o & 127;
      int cbl = cb ^ ((row & 7) << 4);
      int rA = m0 + row;
      rA = rA < M ? rA : 0;
      gload16((const char*)A + (size_t)rA * 512 + k0b + cbl,
              Als + i * 4096 + (t & 192) * 16);
      gload16((const char*)WT + (size_t)(nb + row) * 512 + k0b + cbl,
              Bls + i * 4096 + (t & 192) * 16);
    }
    __syncthreads();
#pragma unroll
    for (int ks = 0; ks < 2; ++ks) {
      bf16x8 af[4], bfv[4];
#pragma unroll
      for (int mi = 0; mi < 4; ++mi) {
        int ra = wr * 64 + mi * 16 + lrow;
        int cba = (ks * 64 + lg * 16) ^ ((ra & 7) << 4);
        af[mi] = *(const bf16x8*)(Als + ra * 128 + cba);
        int rb = wc * 64 + mi * 16 + lrow;
        int cbb = (ks * 64 + lg * 16) ^ ((rb & 7) << 4);
        bfv[mi] = *(const bf16x8*)(Bls + rb * 128 + cbb);
      }
#pragma unroll
      for (int mi = 0; mi < 4; ++mi)
#pragma unroll
        for (int ni = 0; ni < 4; ++ni)
          acc[mi][ni] = __builtin_amdgcn_mfma_f32_16x16x32_bf16(af[mi], bfv[ni], acc[mi][ni], 0, 0, 0);
    }
    __syncthreads();
  }

  double ps[4] = {0, 0, 0, 0}, pq[4] = {0, 0, 0, 0};
#pragma unroll
  for (int mi = 0; mi < 4; ++mi) {
#pragma unroll
    for (int r = 0; r < 4; ++r) {
      int m = m0 + wr * 64 + mi * 16 + lg * 4 + r;
      if (MODE == 0 && m >= M) continue;
      int mk = 0;
      if constexpr (MODE == 3) { mk = maskp[m]; }
#pragma unroll
      for (int ni = 0; ni < 4; ++ni) {
        int n = nb + wc * 64 + ni * 16 + lrow;
        float v = acc[mi][ni][r] + bias[n];
        if constexpr (MODE == 0) {
          out_f32[(size_t)m * 1024 + n] = v;
        } else if constexpr (MODE == 2) {
          float eo = bf2f(out_bf16[(size_t)m * 256 + n]);
          unsigned short nb16 = f2bf(eo + v);
          out_bf16[(size_t)m * 256 + n] = nb16;
          if constexpr (GN) {
            float rv = bf2f(nb16);
            ps[ni] += (double)rv;
            pq[ni] += (double)rv * (double)rv;
          }
        } else {
          v += mask_emb[mk * 256 + n];
          out_bf16[(size_t)m * 256 + n] = f2bf(v);
        }
      }
    }
  }

  if constexpr (GN) {
    __syncthreads();
    double* redS = (double*)lds;           // [128][8] f64 = 8KB
    double* redQ = (double*)(lds + 8192);  // 8KB
    int slot = wr * 4 + lg;
#pragma unroll
    for (int ni = 0; ni < 4; ++ni) {
      int cn = wc * 64 + ni * 16 + lrow;
      redS[cn * 8 + slot] = ps[ni];
      redQ[cn * 8 + slot] = pq[ni];
    }
    __syncthreads();
    if (t < 128) {
      double s = 0, q = 0;
#pragma unroll
      for (int k = 0; k < 8; ++k) { s += redS[t * 8 + k]; q += redQ[t * 8 + k]; }
      atomicAdd(&gnp[nb + t], s);
      atomicAdd(&gnp[H + nb + t], q);
    }
  }
}

// ---------------------------------------------------------------------------
// Fused layer-edge kernel: BM=32 (2 nodes), BN=256, 8 waves (512 thr).
// LDS = max(A 4K + B 32K, enew 32x256 f32) = 36KB -> 4 blocks/CU.
// E0: acc + Cb + Ah[col] + Bh[row] -> enew (XOR-swizzled f32)
// E1: node update (waves 0-1, one node each)
// E2: double-LN+silu -> bout bf16 (all 8 waves, 4 rows each)
// ---------------------------------------------------------------------------
__global__ __launch_bounds__(512, 8) void k_layer_edge(const unsigned short* __restrict__ A,
                                                       const unsigned short* __restrict__ WT,
                                                       const float* __restrict__ Cb,
                                                       const int* __restrict__ ei_col,
                                                       const float* __restrict__ XW,
                                                       const float* __restrict__ nhg, const float* __restrict__ nhb,
                                                       const float* __restrict__ neg_, const float* __restrict__ neb_,
                                                       const float* __restrict__ tvec_l,
                                                       const float* __restrict__ pg_, const float* __restrict__ pb_,
                                                       float* __restrict__ x, unsigned short* __restrict__ xb,
                                                       unsigned short* __restrict__ bout) {
  const int t = threadIdx.x;
  const int m0 = blockIdx.x * 32;
  const int lane = t & 63;
  const int wave = t >> 6;      // 8 col-groups of 32 cols each
  const int wc = wave;
  const int lrow = lane & 15, lg = lane >> 4;
  const int c0 = lane * 4;

  __shared__ __align__(16) char lds[36864];
  char* Als = lds;            // [32][128B] swizzled (GEMM phase)
  char* Bls = lds + 4096;     // [256][128B] swizzled (GEMM phase)
  float* enew = (float*)lds;  // [32][256] f32 swizzled (epilogue)

  f32x4 acc[2][2];
#pragma unroll
  for (int i = 0; i < 2; ++i)
#pragma unroll
    for (int j = 0; j < 2; ++j) acc[i][j] = (f32x4)0.0f;

  const int wave_off = wave * 1024;
  for (int kt = 0; kt < 4; ++kt) {
    const int k0b = kt * 128;
    if (t < 256) {  // A: 32 rows x 128B = 4KB
      int o = t * 16;
      int row = o >> 7;
      int cbl = (o & 127) ^ ((row & 7) << 4);
      gload16((const char*)A + (size_t)(m0 + row) * 512 + k0b + cbl, Als + wave_off);
    }
#pragma unroll
    for (int c = 0; c < 4; ++c) {  // B: 256 rows x 128B = 32KB
      int o = c * 8192 + t * 16;
      int row = o >> 7;
      int cbl = (o & 127) ^ ((row & 7) << 4);
      gload16((const char*)WT + (size_t)row * 512 + k0b + cbl, Bls + c * 8192 + wave_off);
    }
    __syncthreads();
#pragma unroll
    for (int ks = 0; ks < 2; ++ks) {
      bf16x8 af[2], bfv[2];
#pragma unroll
      for (int mi = 0; mi < 2; ++mi) {
        int ra = mi * 16 + lrow;
        af[mi] = *(const bf16x8*)(Als + ra * 128 + ((ks * 64 + lg * 16) ^ ((ra & 7) << 4)));
      }
#pragma unroll
      for (int ni = 0; ni < 2; ++ni) {
        int rb = wc * 32 + ni * 16 + lrow;
        bfv[ni] = *(const bf16x8*)(Bls + rb * 128 + ((ks * 64 + lg * 16) ^ ((rb & 7) << 4)));
      }
#pragma unroll
      for (int mi = 0; mi < 2; ++mi)
#pragma unroll
        for (int ni = 0; ni < 2; ++ni)
          acc[mi][ni] = __builtin_amdgcn_mfma_f32_16x16x32_bf16(af[mi], bfv[ni], acc[mi][ni], 0, 0, 0);
    }
    __syncthreads();
  }

  // ---- E0: acc + Cb + Ah[col] + Bh[node] -> enew (swizzled f32) ----
  {
    float bs[2];
#pragma unroll
    for (int ni = 0; ni < 2; ++ni) bs[ni] = Cb[wc * 32 + ni * 16 + lrow];
#pragma unroll
    for (int mi = 0; mi < 2; ++mi) {
#pragma unroll
      for (int r = 0; r < 4; ++r) {
        int ml = mi * 16 + lg * 4 + r;
        int m = m0 + ml;
        int cv = ei_col[m];
        const float* AhR = XW + (size_t)cv * 1024 + 512;
        const float* BhR = XW + (size_t)(m >> 4) * 1024 + 768;
        int sw = (ml & 15) << 2;
#pragma unroll
        for (int ni = 0; ni < 2; ++ni) {
          int n = wc * 32 + ni * 16 + lrow;
          enew[ml * 256 + (n ^ sw)] = acc[mi][ni][r] + bs[ni] + AhR[n] + BhR[n];
        }
      }
    }
  }
  __syncthreads();

  // ---- E1: node update (waves 0-1, one node each) ----
  if (wave < 2) {
    int v = (m0 >> 4) + wave;
    f32x4 agg = (f32x4)0.0f;
#pragma unroll 4
    for (int k = 0; k < K_DEG; ++k) {
      int row = wave * 16 + k;
      int cv = ei_col[m0 + row];
      f32x4 en = *(const f32x4*)&enew[row * 256 + (c0 ^ ((row & 15) << 2))];
      f32x4 vh = *(const f32x4*)&XW[(size_t)cv * 1024 + 256 + c0];
#pragma unroll
      for (int i = 0; i < 4; ++i) agg[i] += vh[i] * fsig(en[i]);
    }
    f32x4 s4 = *(const f32x4*)&XW[(size_t)v * 1024 + c0];  // Uh
    s4 += agg;
    float s = s4[0] + s4[1] + s4[2] + s4[3];
    float sq = s4[0] * s4[0] + s4[1] * s4[1] + s4[2] * s4[2] + s4[3] * s4[3];
#pragma unroll
    for (int st = 1; st < 64; st <<= 1) { s += __shfl_xor(s, st); sq += __shfl_xor(sq, st); }
    float mean = s * (1.0f / H);
    float inv = rsqrtf(sq * (1.0f / H) - mean * mean + 1e-5f);
    f32x4 g = *(const f32x4*)&nhg[c0];
    f32x4 bb = *(const f32x4*)&nhb[c0];
    f32x4 xo = *(const f32x4*)&x[(size_t)v * H + c0];
    u16x4 ov;
#pragma unroll
    for (int i = 0; i < 4; ++i) {
      float h = fmaxf((s4[i] - mean) * inv * g[i] + bb[i], 0.0f);
      xo[i] += h;
      ov[i] = f2bf(xo[i]);
    }
    *(f32x4*)&x[(size_t)v * H + c0] = xo;
    *(u16x4*)&xb[(size_t)v * H + c0] = ov;
  }

  // ---- E2: double-LN + silu chain -> bout bf16 (4 rows per wave) ----
  {
    f32x4 g1 = *(const f32x4*)&neg_[c0];
    f32x4 b1 = *(const f32x4*)&neb_[c0];
    f32x4 tv = *(const f32x4*)&tvec_l[c0];
    f32x4 g2 = *(const f32x4*)&pg_[c0];
    f32x4 b2 = *(const f32x4*)&pb_[c0];
#pragma unroll
    for (int k = 0; k < 4; ++k) {
      int row = wave + 8 * k;
      f32x4 vv = *(const f32x4*)&enew[row * 256 + (c0 ^ ((row & 15) << 2))];
      float s = vv[0] + vv[1] + vv[2] + vv[3];
      float sq = vv[0] * vv[0] + vv[1] * vv[1] + vv[2] * vv[2] + vv[3] * vv[3];
#pragma unroll
      for (int st = 1; st < 64; st <<= 1) { s += __shfl_xor(s, st); sq += __shfl_xor(sq, st); }
      float mean = s * (1.0f / H);
      float inv = rsqrtf(sq * (1.0f / H) - mean * mean + 1e-5f);
      f32x4 a;
#pragma unroll
      for (int i = 0; i < 4; ++i) a[i] = fmaxf((vv[i] - mean) * inv * g1[i] + b1[i], 0.0f) + tv[i];
      s = a[0] + a[1] + a[2] + a[3];
      sq = a[0] * a[0] + a[1] * a[1] + a[2] * a[2] + a[3] * a[3];
#pragma unroll
      for (int st = 1; st < 64; st <<= 1) { s += __shfl_xor(s, st); sq += __shfl_xor(sq, st); }
      mean = s * (1.0f / H);
      inv = rsqrtf(sq * (1.0f / H) - mean * mean + 1e-5f);
      u16x4 ov;
#pragma unroll
      for (int i = 0; i < 4; ++i) {
        float n = (a[i] - mean) * inv * g2[i] + b2[i];
        ov[i] = f2bf(n * fsig(n));
      }
      *(u16x4*)&bout[(size_t)(m0 + row) * H + c0] = ov;
    }
  }
}

__global__ void k_gn_finalize(const double* __restrict__ sums, float* __restrict__ gstats) {
  int g = threadIdx.x;
  if (g < 32) {
    double s = 0.0, sq = 0.0;
    for (int c = g * 8; c < g * 8 + 8; ++c) {
      s += sums[c];
      sq += sums[H + c];
    }
    double n = 8.0 * (double)E_EDGES;
    double mean = s / n;
    double var = sq / n - mean * mean;
    gstats[g] = (float)mean;
    gstats[32 + g] = (float)(1.0 / sqrt(var + 1e-5));
  }
}

__global__ __launch_bounds__(256) void k_head(const unsigned short* __restrict__ e_bf,
                                              const float* __restrict__ gstats,
                                              const float* __restrict__ gn_g, const float* __restrict__ gn_b,
                                              const float* __restrict__ out_w, const float* __restrict__ out_b,
                                              float* __restrict__ out) {
  int wv = threadIdx.x >> 6;
  int lane = threadIdx.x & 63;
  int eid = blockIdx.x * 4 + wv;
  int c0 = lane * 4;
  u16x4 ev = *(const u16x4*)&e_bf[(size_t)eid * H + c0];
  float a0 = 0.0f, a1 = 0.0f;
#pragma unroll
  for (int i = 0; i < 4; ++i) {
    int c = c0 + i;
    int g = c >> 3;
    float v = (bf2f(ev[i]) - gstats[g]) * gstats[32 + g] * gn_g[c] + gn_b[c];
    v = fmaxf(v, 0.0f);
    a0 += v * out_w[c * 2 + 0];
    a1 += v * out_w[c * 2 + 1];
  }
  for (int s = 32; s > 0; s >>= 1) {
    a0 += __shfl_down(a0, s);
    a1 += __shfl_down(a1, s);
  }
  if (lane == 0) {
    out[(size_t)eid * 2 + 0] = a0 + out_b[0];
    out[(size_t)eid * 2 + 1] = a1 + out_b[1];
  }
}

// ---------------------------------------------------------------------------
extern "C" void kernel_launch(void* const* d_in, const int* in_sizes, int n_in,
                              void* d_out, int out_size, void* d_ws, size_t ws_size,
                              hipStream_t stream) {
  const float* nodes_feature = (const float*)d_in[0];
  const float* e_vals = (const float*)d_in[1];
  const int* mask = (const int*)d_in[2];
  const int* t = (const int*)d_in[3];
  const int* edge_index = (const int*)d_in[4];
  const float* node_w = (const float*)d_in[5];
  const float* node_b = (const float*)d_in[6];
  const float* edge_w = (const float*)d_in[7];
  const float* edge_b = (const float*)d_in[8];
  const float* te1_w = (const float*)d_in[9];
  const float* te1_b = (const float*)d_in[10];
  const float* te2_w = (const float*)d_in[11];
  const float* te2_b = (const float*)d_in[12];
  const float* U_w = (const float*)d_in[13];
  const float* U_b = (const float*)d_in[14];
  const float* V_w = (const float*)d_in[15];
  const float* V_b = (const float*)d_in[16];
  const float* A_w = (const float*)d_in[17];
  const float* A_b = (const float*)d_in[18];
  const float* B_w = (const float*)d_in[19];
  const float* B_b = (const float*)d_in[20];
  const float* C_w = (const float*)d_in[21];
  const float* C_b = (const float*)d_in[22];
  const float* nh_g = (const float*)d_in[23];
  const float* nh_b = (const float*)d_in[24];
  const float* ne_g = (const float*)d_in[25];
  const float* ne_b = (const float*)d_in[26];
  const float* tl_w = (const float*)d_in[27];
  const float* tl_b = (const float*)d_in[28];
  const float* plo_g = (const float*)d_in[29];
  const float* plo_b = (const float*)d_in[30];
  const float* plo_w = (const float*)d_in[31];
  const float* plo_b2 = (const float*)d_in[32];
  const float* gn_g = (const float*)d_in[33];
  const float* gn_b = (const float*)d_in[34];
  const float* out_w = (const float*)d_in[35];
  const float* out_b = (const float*)d_in[36];
  const float* mask_emb = (const float*)d_in[37];

  char* wsb = (char*)d_ws;
  size_t off = 0;
  auto alloc = [&](size_t bytes) -> void* {
    void* p = wsb + off;
    off += (bytes + 255) & ~(size_t)255;
    return p;
  };
  double* gn_sums = (double*)alloc(512 * sizeof(double));
  float* XW = (float*)alloc((size_t)V_NODES * 1024 * 4);
  unsigned short* e_bf = (unsigned short*)alloc((size_t)E_EDGES * H * 2);
  unsigned short* pe_b = (unsigned short*)alloc((size_t)E_EDGES * H * 2);
  unsigned short* x_bf = (unsigned short*)alloc((size_t)V_NODES * H * 2);
  unsigned short* WT4 = (unsigned short*)alloc((size_t)L_LAYERS * 1024 * H * 2);
  unsigned short* WTC = (unsigned short*)alloc((size_t)L_LAYERS * H * H * 2);
  unsigned short* WTplo = (unsigned short*)alloc((size_t)L_LAYERS * H * H * 2);
  unsigned short* WTedge = (unsigned short*)alloc((size_t)H * H * 2);
  float* b4 = (float*)alloc((size_t)L_LAYERS * 1024 * 4);
  float* tvec = (float*)alloc((size_t)L_LAYERS * H * 4);
  float* gstats = (float*)alloc(64 * 4);

  const int* ei_col = edge_index + E_EDGES;

  float* x = (float*)d_out;
  float* out2 = (float*)d_out + (size_t)V_NODES * H;

  // Merged preamble: prep_w | prep_b | node_embed | pe | temb+tvec
  k_pre<<<16192, 256, 0, stream>>>(U_w, V_w, A_w, B_w, C_w, plo_w, edge_w,
                                   WT4, WTC, WTplo, WTedge,
                                   U_b, V_b, A_b, B_b, b4,
                                   nodes_feature, node_w, node_b, x, x_bf,
                                   e_vals, pe_b,
                                   t, te1_w, te1_b, te2_w, te2_b, tl_w, tl_b, tvec);
  k_gemm<3, false><<<dim3(E_EDGES / 128, 2), 256, 0, stream>>>(pe_b, WTedge, E_EDGES, edge_b, mask, mask_emb,
                                                               nullptr, e_bf, nullptr);
  hipMemsetAsync(gn_sums, 0, 512 * sizeof(double), stream);

  for (int l = 0; l < L_LAYERS; ++l) {
    size_t wo = (size_t)l * H * H;
    size_t bo = (size_t)l * H;
    k_gemm<0, false><<<dim3(24, 8), 256, 0, stream>>>(x_bf, WT4 + (size_t)l * 1024 * H, V_NODES, b4 + l * 1024,
                                                      nullptr, nullptr, XW, nullptr, nullptr);
    k_layer_edge<<<E_EDGES / 32, 512, 0, stream>>>(e_bf, WTC + wo, C_b + bo, ei_col, XW,
                                                   nh_g + bo, nh_b + bo, ne_g + bo, ne_b + bo, tvec + bo,
                                                   plo_g + bo, plo_b + bo, x, x_bf, pe_b);
    if (l == L_LAYERS - 1) {
      k_gemm<2, true><<<dim3(E_EDGES / 128, 2), 256, 0, stream>>>(pe_b, WTplo + wo, E_EDGES, plo_b2 + bo,
                                                                  nullptr, nullptr, nullptr, e_bf, gn_sums);
    } else {
      k_gemm<2, false><<<dim3(E_EDGES / 128, 2), 256, 0, stream>>>(pe_b, WTplo + wo, E_EDGES, plo_b2 + bo,
                                                                   nullptr, nullptr, nullptr, e_bf, nullptr);
    }
  }

  k_gn_finalize<<<1, 64, 0, stream>>>(gn_sums, gstats);
  k_head<<<E_EDGES / 4, 256, 0, stream>>>(e_bf, gstats, gn_g, gn_b, out_w, out_b, out2);
}

// Round 11
// 765.585 us; speedup vs baseline: 1.1509x; 1.0354x over previous
//
#include <hip/hip_runtime.h>
#include <math.h>

#define V_NODES 3000
#define K_DEG 16
#define E_EDGES 48000
#define H 256
#define TE 128
#define L_LAYERS 12

typedef __attribute__((ext_vector_type(4))) float f32x4;
typedef __attribute__((ext_vector_type(8))) __bf16 bf16x8;
typedef __attribute__((ext_vector_type(4))) unsigned short u16x4;

__device__ __forceinline__ unsigned short f2bf(float f) {
  unsigned u = __float_as_uint(f);
  unsigned r = (u + 0x7fffu + ((u >> 16) & 1u)) >> 16;
  return (unsigned short)r;
}

__device__ __forceinline__ float bf2f(unsigned short u) {
  return __uint_as_float(((unsigned)u) << 16);
}

// fast sigmoid: 1/(1+2^(-x*log2e)) via v_exp_f32 + v_rcp_f32 (~1e-6 rel err)
__device__ __forceinline__ float fsig(float x) {
  return __builtin_amdgcn_rcpf(1.0f + __builtin_amdgcn_exp2f(-1.4426950408889634f * x));
}

// HW sin/cos: v_sin_f32/v_cos_f32 take REVOLUTIONS (sin(x*2pi))
__device__ __forceinline__ float hsin(float rev) { return __builtin_amdgcn_sinf(rev); }
__device__ __forceinline__ float hcos(float rev) { return __builtin_amdgcn_cosf(rev); }

__device__ __forceinline__ void gload16(const void* g, void* l) {
  __builtin_amdgcn_global_load_lds((const __attribute__((address_space(1))) void*)g,
                                   (__attribute__((address_space(3))) void*)l, 16, 0, 0);
}

// ---------------------------------------------------------------------------
// Preamble bodies (merged into one uber-dispatch k_pre):
//  [0,1168)      prep_w ; [1168,1180) prep_b ; [1180,4180) node_embed ;
//  [4180,16180)  pe ; [16180,16192) temb+tvec
// ---------------------------------------------------------------------------
__device__ void prep_w_body(char* ldsraw, int bid,
                            const float* __restrict__ U_w, const float* __restrict__ V_w,
                            const float* __restrict__ A_w, const float* __restrict__ B_w,
                            const float* __restrict__ C_w, const float* __restrict__ plo_w,
                            const float* __restrict__ edge_w,
                            unsigned short* __restrict__ WT4, unsigned short* __restrict__ WTC,
                            unsigned short* __restrict__ WTplo, unsigned short* __restrict__ WTedge) {
  const float* src;
  unsigned short* dst;
  int tt;
  if (bid < 768) {
    int l = bid >> 6;
    int rem = bid & 63;
    int mat = rem >> 4;
    tt = rem & 15;
    const float* srcs[4] = {U_w, V_w, A_w, B_w};
    src = srcs[mat] + (size_t)l * H * H;
    dst = WT4 + (size_t)l * 1024 * H + (size_t)mat * H * H;
  } else if (bid < 960) {
    int b2 = bid - 768;
    int l = b2 >> 4;
    tt = b2 & 15;
    src = C_w + (size_t)l * H * H;
    dst = WTC + (size_t)l * H * H;
  } else if (bid < 1152) {
    int b2 = bid - 960;
    int l = b2 >> 4;
    tt = b2 & 15;
    src = plo_w + (size_t)l * H * H;
    dst = WTplo + (size_t)l * H * H;
  } else {
    tt = bid - 1152;
    src = edge_w;
    dst = WTedge;
  }
  int k0 = (tt & 3) * 64, n0 = (tt >> 2) * 64;
  float (*ts)[65] = (float(*)[65])ldsraw;
  int c = threadIdx.x & 63;
  int r0 = threadIdx.x >> 6;
  for (int rr = 0; rr < 64; rr += 4) {
    int r = rr + r0;
    ts[r][c] = src[(size_t)(k0 + r) * H + n0 + c];
  }
  __syncthreads();
  for (int nn = 0; nn < 64; nn += 4) {
    int n = nn + r0;
    dst[(size_t)(n0 + n) * H + k0 + c] = f2bf(ts[c][n]);
  }
}

__device__ void prep_b_body(int l,
                            const float* __restrict__ U_b, const float* __restrict__ V_b,
                            const float* __restrict__ A_b, const float* __restrict__ B_b,
                            float* __restrict__ b4) {
  int t = threadIdx.x;
  b4[l * 1024 + 0 + t] = U_b[l * H + t];
  b4[l * 1024 + 256 + t] = V_b[l * H + t];
  b4[l * 1024 + 512 + t] = A_b[l * H + t];
  b4[l * 1024 + 768 + t] = B_b[l * H + t];
}

__device__ void node_embed_body(char* ldsraw, int v,
                                const float* __restrict__ coords,
                                const float* __restrict__ W,
                                const float* __restrict__ b,
                                float* __restrict__ x,
                                unsigned short* __restrict__ xb) {
  int j = threadIdx.x;
  float4* pe4 = (float4*)ldsraw;
  // sin(coord*2pi / dim_t) = hw_sin(coord / dim_t)  [revolutions]
  float cy = coords[v * 2 + 0];
  float cx = coords[v * 2 + 1];
  int idx = j & 127;
  float coord = (j < 128) ? cy : cx;
  float invd = __builtin_amdgcn_exp2f(-13.287712379549449f * (float)(2 * (idx >> 1)) * (1.0f / 128.0f));
  float rev = coord * invd;
  ((float*)pe4)[j] = (idx & 1) ? hcos(rev) : hsin(rev);
  __syncthreads();
  float acc = b[j];
  for (int k4 = 0; k4 < H / 4; ++k4) {
    float4 p = pe4[k4];
    int k = 4 * k4;
    acc += p.x * W[(k + 0) * H + j] + p.y * W[(k + 1) * H + j] +
           p.z * W[(k + 2) * H + j] + p.w * W[(k + 3) * H + j];
  }
  x[(size_t)v * H + j] = acc;
  xb[(size_t)v * H + j] = f2bf(acc);
}

__device__ void pe_body(int b, const float* __restrict__ e_vals, unsigned short* __restrict__ pe) {
  int eid = b * 4 + (threadIdx.x >> 6);
  int lane = threadIdx.x & 63;
  int c0 = lane * 4;
  float val = e_vals[eid];
  const float lg = 13.287712379549449f / 256.0f;
  u16x4 ov;
#pragma unroll
  for (int i = 0; i < 4; ++i) {
    int c = c0 + i;
    float invd = __builtin_amdgcn_exp2f(-(float)(c & ~1) * lg);
    float rev = val * invd * 0.15915494309189535f;  // radians -> revolutions
    float s = (c & 1) ? hcos(rev) : hsin(rev);
    ov[i] = f2bf(s);
  }
  *(u16x4*)&pe[(size_t)eid * H + c0] = ov;
}

__device__ void temb_tvec_body(char* ldsraw, int l,
                               const int* __restrict__ t,
                               const float* __restrict__ te1_w, const float* __restrict__ te1_b,
                               const float* __restrict__ te2_w, const float* __restrict__ te2_b,
                               const float* __restrict__ tl_w, const float* __restrict__ tl_b,
                               float* __restrict__ tvec) {
  float* emb = (float*)ldsraw;            // [256]
  float* h1 = (float*)(ldsraw + 1024);    // [128]
  float* rt = (float*)(ldsraw + 1536);    // [128]
  int j = threadIdx.x;
  float tv = (float)t[0];
  {
    int i = j & 127;
    float f = expf(-logf(10000.0f) * (float)i / 128.0f);
    float arg = tv * f;
    emb[j] = (j < 128) ? cosf(arg) : sinf(arg);
  }
  __syncthreads();
  if (j < TE) {
    float acc = te1_b[j];
    for (int k = 0; k < H; ++k) acc += emb[k] * te1_w[k * TE + j];
    h1[j] = fmaxf(acc, 0.0f);
  }
  __syncthreads();
  if (j < TE) {
    float acc = te2_b[j];
    for (int k = 0; k < TE; ++k) acc += h1[k] * te2_w[k * TE + j];
    rt[j] = fmaxf(acc, 0.0f);  // relu(temb)
  }
  __syncthreads();
  float acc = tl_b[l * H + j];
  for (int k = 0; k < TE; ++k) acc += rt[k] * tl_w[(size_t)(l * TE + k) * H + j];
  tvec[l * H + j] = acc;
}

__global__ __launch_bounds__(256) void k_pre(const float* __restrict__ U_w, const float* __restrict__ V_w,
                                             const float* __restrict__ A_w, const float* __restrict__ B_w,
                                             const float* __restrict__ C_w, const float* __restrict__ plo_w,
                                             const float* __restrict__ edge_w,
                                             unsigned short* __restrict__ WT4, unsigned short* __restrict__ WTC,
                                             unsigned short* __restrict__ WTplo, unsigned short* __restrict__ WTedge,
                                             const float* __restrict__ U_b, const float* __restrict__ V_b,
                                             const float* __restrict__ A_b, const float* __restrict__ B_b,
                                             float* __restrict__ b4,
                                             const float* __restrict__ coords,
                                             const float* __restrict__ node_w, const float* __restrict__ node_b,
                                             float* __restrict__ x, unsigned short* __restrict__ xb,
                                             const float* __restrict__ e_vals, unsigned short* __restrict__ pe,
                                             const int* __restrict__ t,
                                             const float* __restrict__ te1_w, const float* __restrict__ te1_b,
                                             const float* __restrict__ te2_w, const float* __restrict__ te2_b,
                                             const float* __restrict__ tl_w, const float* __restrict__ tl_b,
                                             float* __restrict__ tvec) {
  __shared__ __align__(16) char lds[16896];
  int b = blockIdx.x;
  if (b < 1168) {
    prep_w_body(lds, b, U_w, V_w, A_w, B_w, C_w, plo_w, edge_w, WT4, WTC, WTplo, WTedge);
  } else if (b < 1180) {
    prep_b_body(b - 1168, U_b, V_b, A_b, B_b, b4);
  } else if (b < 4180) {
    node_embed_body(lds, b - 1180, coords, node_w, node_b, x, xb);
  } else if (b < 16180) {
    pe_body(b - 4180, e_vals, pe);
  } else {
    temb_tvec_body(lds, b - 16180, t, te1_w, te1_b, te2_w, te2_b, tl_w, tl_b, tvec);
  }
}

// ---------------------------------------------------------------------------
// Plain MFMA GEMM (128x128 tile, 4 waves, BK=64) for modes 2/3.
// MODE 2: edge plo  -> e_bf += acc + bias (bf16 storage); GN: fused stats
// MODE 3: edge embed-> acc + bias + mask_emb[mask[m]] -> e_bf
// ---------------------------------------------------------------------------
template <int MODE, bool GN>
__global__ __launch_bounds__(256) void k_gemm(const unsigned short* __restrict__ A,
                                              const unsigned short* __restrict__ WT,
                                              int M,
                                              const float* __restrict__ bias,
                                              const int* __restrict__ maskp,
                                              const float* __restrict__ mask_emb,
                                              float* __restrict__ out_f32,
                                              unsigned short* __restrict__ out_bf16,
                                              double* __restrict__ gnp) {
  const int t = threadIdx.x;
  const int m0 = blockIdx.x * 128;
  const int nb = blockIdx.y * 128;
  const int lane = t & 63;
  const int wave = t >> 6;
  const int wr = wave >> 1, wc = wave & 1;
  const int lrow = lane & 15, lg = lane >> 4;

  __shared__ __align__(16) char lds[32768];
  char* Als = lds;
  char* Bls = lds + 16384;

  f32x4 acc[4][4];
#pragma unroll
  for (int i = 0; i < 4; ++i)
#pragma unroll
    for (int j = 0; j < 4; ++j) acc[i][j] = (f32x4)0.0f;

  for (int kt = 0; kt < 4; ++kt) {
    const int k0b = kt * 128;
#pragma unroll
    for (int i = 0; i < 4; ++i) {
      int o = i * 4096 + t * 16;
      int row = o >> 7;
      int cb = o & 127;
      int cbl = cb ^ ((row & 7) << 4);
      int rA = m0 + row;
      rA = rA < M ? rA : 0;
      gload16((const char*)A + (size_t)rA * 512 + k0b + cbl,
              Als + i * 4096 + (t & 192) * 16);
      gload16((const char*)WT + (size_t)(nb + row) * 512 + k0b + cbl,
              Bls + i * 4096 + (t & 192) * 16);
    }
    __syncthreads();
#pragma unroll
    for (int ks = 0; ks < 2; ++ks) {
      bf16x8 af[4], bfv[4];
#pragma unroll
      for (int mi = 0; mi < 4; ++mi) {
        int ra = wr * 64 + mi * 16 + lrow;
        int cba = (ks * 64 + lg * 16) ^ ((ra & 7) << 4);
        af[mi] = *(const bf16x8*)(Als + ra * 128 + cba);
        int rb = wc * 64 + mi * 16 + lrow;
        int cbb = (ks * 64 + lg * 16) ^ ((rb & 7) << 4);
        bfv[mi] = *(const bf16x8*)(Bls + rb * 128 + cbb);
      }
#pragma unroll
      for (int mi = 0; mi < 4; ++mi)
#pragma unroll
        for (int ni = 0; ni < 4; ++ni)
          acc[mi][ni] = __builtin_amdgcn_mfma_f32_16x16x32_bf16(af[mi], bfv[ni], acc[mi][ni], 0, 0, 0);
    }
    __syncthreads();
  }

  double ps[4] = {0, 0, 0, 0}, pq[4] = {0, 0, 0, 0};
#pragma unroll
  for (int mi = 0; mi < 4; ++mi) {
#pragma unroll
    for (int r = 0; r < 4; ++r) {
      int m = m0 + wr * 64 + mi * 16 + lg * 4 + r;
      int mk = 0;
      if constexpr (MODE == 3) { mk = maskp[m]; }
#pragma unroll
      for (int ni = 0; ni < 4; ++ni) {
        int n = nb + wc * 64 + ni * 16 + lrow;
        float v = acc[mi][ni][r] + bias[n];
        if constexpr (MODE == 2) {
          float eo = bf2f(out_bf16[(size_t)m * 256 + n]);
          unsigned short nb16 = f2bf(eo + v);
          out_bf16[(size_t)m * 256 + n] = nb16;
          if constexpr (GN) {
            float rv = bf2f(nb16);
            ps[ni] += (double)rv;
            pq[ni] += (double)rv * (double)rv;
          }
        } else {
          v += mask_emb[mk * 256 + n];
          out_bf16[(size_t)m * 256 + n] = f2bf(v);
        }
      }
    }
  }

  if constexpr (GN) {
    __syncthreads();
    double* redS = (double*)lds;           // [128][8] f64 = 8KB
    double* redQ = (double*)(lds + 8192);  // 8KB
    int slot = wr * 4 + lg;
#pragma unroll
    for (int ni = 0; ni < 4; ++ni) {
      int cn = wc * 64 + ni * 16 + lrow;
      redS[cn * 8 + slot] = ps[ni];
      redQ[cn * 8 + slot] = pq[ni];
    }
    __syncthreads();
    if (t < 128) {
      double s = 0, q = 0;
#pragma unroll
      for (int k = 0; k < 8; ++k) { s += redS[t * 8 + k]; q += redQ[t * 8 + k]; }
      atomicAdd(&gnp[nb + t], s);
      atomicAdd(&gnp[H + nb + t], q);
    }
  }
}

// ---------------------------------------------------------------------------
// Node UVAB GEMM: BM=128, BN=64, BK=64, 4 waves; grid (24,16) = 384 blocks
// (2x the old 192 -> better latency hiding on the small node GEMM).
// out_f32[m*1024 + nb+n] = acc + bias[nb+n]
// ---------------------------------------------------------------------------
__global__ __launch_bounds__(256) void k_gemm0(const unsigned short* __restrict__ A,
                                               const unsigned short* __restrict__ WT,
                                               const float* __restrict__ bias,
                                               float* __restrict__ out_f32) {
  const int t = threadIdx.x;
  const int m0 = blockIdx.x * 128;
  const int nb = blockIdx.y * 64;
  const int lane = t & 63;
  const int wave = t >> 6;
  const int lrow = lane & 15, lg = lane >> 4;

  __shared__ __align__(16) char lds[24576];
  char* Als = lds;           // [128][128B] swizzled
  char* Bls = lds + 16384;   // [64][128B] swizzled

  f32x4 acc[2][4];
#pragma unroll
  for (int i = 0; i < 2; ++i)
#pragma unroll
    for (int j = 0; j < 4; ++j) acc[i][j] = (f32x4)0.0f;

  for (int kt = 0; kt < 4; ++kt) {
    const int k0b = kt * 128;
#pragma unroll
    for (int i = 0; i < 4; ++i) {  // A: 128 rows x 128B = 16KB
      int o = i * 4096 + t * 16;
      int row = o >> 7;
      int cbl = (o & 127) ^ ((row & 7) << 4);
      int rA = m0 + row;
      rA = rA < V_NODES ? rA : 0;
      gload16((const char*)A + (size_t)rA * 512 + k0b + cbl,
              Als + i * 4096 + (t & 192) * 16);
    }
#pragma unroll
    for (int c = 0; c < 2; ++c) {  // B: 64 rows x 128B = 8KB
      int o = c * 4096 + t * 16;
      int row = o >> 7;
      int cbl = (o & 127) ^ ((row & 7) << 4);
      gload16((const char*)WT + (size_t)(nb + row) * 512 + k0b + cbl,
              Bls + c * 4096 + (t & 192) * 16);
    }
    __syncthreads();
#pragma unroll
    for (int ks = 0; ks < 2; ++ks) {
      bf16x8 af[2], bfv[4];
#pragma unroll
      for (int mi = 0; mi < 2; ++mi) {
        int ra = wave * 32 + mi * 16 + lrow;
        af[mi] = *(const bf16x8*)(Als + ra * 128 + ((ks * 64 + lg * 16) ^ ((ra & 7) << 4)));
      }
#pragma unroll
      for (int ni = 0; ni < 4; ++ni) {
        int rb = ni * 16 + lrow;
        bfv[ni] = *(const bf16x8*)(Bls + rb * 128 + ((ks * 64 + lg * 16) ^ ((rb & 7) << 4)));
      }
#pragma unroll
      for (int mi = 0; mi < 2; ++mi)
#pragma unroll
        for (int ni = 0; ni < 4; ++ni)
          acc[mi][ni] = __builtin_amdgcn_mfma_f32_16x16x32_bf16(af[mi], bfv[ni], acc[mi][ni], 0, 0, 0);
    }
    __syncthreads();
  }

#pragma unroll
  for (int mi = 0; mi < 2; ++mi) {
#pragma unroll
    for (int r = 0; r < 4; ++r) {
      int m = m0 + wave * 32 + mi * 16 + lg * 4 + r;
      if (m >= V_NODES) continue;
#pragma unroll
      for (int ni = 0; ni < 4; ++ni) {
        int n = nb + ni * 16 + lrow;
        out_f32[(size_t)m * 1024 + n] = acc[mi][ni][r] + bias[n];
      }
    }
  }
}

// ---------------------------------------------------------------------------
// Fused layer-edge kernel: BM=32 (2 nodes), BN=256, 8 waves (512 thr).
// ---------------------------------------------------------------------------
__global__ __launch_bounds__(512, 8) void k_layer_edge(const unsigned short* __restrict__ A,
                                                       const unsigned short* __restrict__ WT,
                                                       const float* __restrict__ Cb,
                                                       const int* __restrict__ ei_col,
                                                       const float* __restrict__ XW,
                                                       const float* __restrict__ nhg, const float* __restrict__ nhb,
                                                       const float* __restrict__ neg_, const float* __restrict__ neb_,
                                                       const float* __restrict__ tvec_l,
                                                       const float* __restrict__ pg_, const float* __restrict__ pb_,
                                                       float* __restrict__ x, unsigned short* __restrict__ xb,
                                                       unsigned short* __restrict__ bout) {
  const int t = threadIdx.x;
  const int m0 = blockIdx.x * 32;
  const int lane = t & 63;
  const int wave = t >> 6;      // 8 col-groups of 32 cols each
  const int wc = wave;
  const int lrow = lane & 15, lg = lane >> 4;
  const int c0 = lane * 4;

  __shared__ __align__(16) char lds[36864];
  char* Als = lds;            // [32][128B] swizzled (GEMM phase)
  char* Bls = lds + 4096;     // [256][128B] swizzled (GEMM phase)
  float* enew = (float*)lds;  // [32][256] f32 swizzled (epilogue)

  f32x4 acc[2][2];
#pragma unroll
  for (int i = 0; i < 2; ++i)
#pragma unroll
    for (int j = 0; j < 2; ++j) acc[i][j] = (f32x4)0.0f;

  const int wave_off = wave * 1024;
  for (int kt = 0; kt < 4; ++kt) {
    const int k0b = kt * 128;
    if (t < 256) {  // A: 32 rows x 128B = 4KB
      int o = t * 16;
      int row = o >> 7;
      int cbl = (o & 127) ^ ((row & 7) << 4);
      gload16((const char*)A + (size_t)(m0 + row) * 512 + k0b + cbl, Als + wave_off);
    }
#pragma unroll
    for (int c = 0; c < 4; ++c) {  // B: 256 rows x 128B = 32KB
      int o = c * 8192 + t * 16;
      int row = o >> 7;
      int cbl = (o & 127) ^ ((row & 7) << 4);
      gload16((const char*)WT + (size_t)row * 512 + k0b + cbl, Bls + c * 8192 + wave_off);
    }
    __syncthreads();
#pragma unroll
    for (int ks = 0; ks < 2; ++ks) {
      bf16x8 af[2], bfv[2];
#pragma unroll
      for (int mi = 0; mi < 2; ++mi) {
        int ra = mi * 16 + lrow;
        af[mi] = *(const bf16x8*)(Als + ra * 128 + ((ks * 64 + lg * 16) ^ ((ra & 7) << 4)));
      }
#pragma unroll
      for (int ni = 0; ni < 2; ++ni) {
        int rb = wc * 32 + ni * 16 + lrow;
        bfv[ni] = *(const bf16x8*)(Bls + rb * 128 + ((ks * 64 + lg * 16) ^ ((rb & 7) << 4)));
      }
#pragma unroll
      for (int mi = 0; mi < 2; ++mi)
#pragma unroll
        for (int ni = 0; ni < 2; ++ni)
          acc[mi][ni] = __builtin_amdgcn_mfma_f32_16x16x32_bf16(af[mi], bfv[ni], acc[mi][ni], 0, 0, 0);
    }
    __syncthreads();
  }

  // ---- E0: acc + Cb + Ah[col] + Bh[node] -> enew (swizzled f32) ----
  {
    float bs[2];
#pragma unroll
    for (int ni = 0; ni < 2; ++ni) bs[ni] = Cb[wc * 32 + ni * 16 + lrow];
#pragma unroll
    for (int mi = 0; mi < 2; ++mi) {
#pragma unroll
      for (int r = 0; r < 4; ++r) {
        int ml = mi * 16 + lg * 4 + r;
        int m = m0 + ml;
        int cv = ei_col[m];
        const float* AhR = XW + (size_t)cv * 1024 + 512;
        const float* BhR = XW + (size_t)(m >> 4) * 1024 + 768;
        int sw = (ml & 15) << 2;
#pragma unroll
        for (int ni = 0; ni < 2; ++ni) {
          int n = wc * 32 + ni * 16 + lrow;
          enew[ml * 256 + (n ^ sw)] = acc[mi][ni][r] + bs[ni] + AhR[n] + BhR[n];
        }
      }
    }
  }
  __syncthreads();

  // ---- E1: node update (waves 0-1, one node each) ----
  if (wave < 2) {
    int v = (m0 >> 4) + wave;
    f32x4 agg = (f32x4)0.0f;
#pragma unroll 4
    for (int k = 0; k < K_DEG; ++k) {
      int row = wave * 16 + k;
      int cv = ei_col[m0 + row];
      f32x4 en = *(const f32x4*)&enew[row * 256 + (c0 ^ ((row & 15) << 2))];
      f32x4 vh = *(const f32x4*)&XW[(size_t)cv * 1024 + 256 + c0];
#pragma unroll
      for (int i = 0; i < 4; ++i) agg[i] += vh[i] * fsig(en[i]);
    }
    f32x4 s4 = *(const f32x4*)&XW[(size_t)v * 1024 + c0];  // Uh
    s4 += agg;
    float s = s4[0] + s4[1] + s4[2] + s4[3];
    float sq = s4[0] * s4[0] + s4[1] * s4[1] + s4[2] * s4[2] + s4[3] * s4[3];
#pragma unroll
    for (int st = 1; st < 64; st <<= 1) { s += __shfl_xor(s, st); sq += __shfl_xor(sq, st); }
    float mean = s * (1.0f / H);
    float inv = rsqrtf(sq * (1.0f / H) - mean * mean + 1e-5f);
    f32x4 g = *(const f32x4*)&nhg[c0];
    f32x4 bb = *(const f32x4*)&nhb[c0];
    f32x4 xo = *(const f32x4*)&x[(size_t)v * H + c0];
    u16x4 ov;
#pragma unroll
    for (int i = 0; i < 4; ++i) {
      float h = fmaxf((s4[i] - mean) * inv * g[i] + bb[i], 0.0f);
      xo[i] += h;
      ov[i] = f2bf(xo[i]);
    }
    *(f32x4*)&x[(size_t)v * H + c0] = xo;
    *(u16x4*)&xb[(size_t)v * H + c0] = ov;
  }

  // ---- E2: double-LN + silu chain -> bout bf16 (4 rows per wave) ----
  {
    f32x4 g1 = *(const f32x4*)&neg_[c0];
    f32x4 b1 = *(const f32x4*)&neb_[c0];
    f32x4 tv = *(const f32x4*)&tvec_l[c0];
    f32x4 g2 = *(const f32x4*)&pg_[c0];
    f32x4 b2 = *(const f32x4*)&pb_[c0];
#pragma unroll
    for (int k = 0; k < 4; ++k) {
      int row = wave + 8 * k;
      f32x4 vv = *(const f32x4*)&enew[row * 256 + (c0 ^ ((row & 15) << 2))];
      float s = vv[0] + vv[1] + vv[2] + vv[3];
      float sq = vv[0] * vv[0] + vv[1] * vv[1] + vv[2] * vv[2] + vv[3] * vv[3];
#pragma unroll
      for (int st = 1; st < 64; st <<= 1) { s += __shfl_xor(s, st); sq += __shfl_xor(sq, st); }
      float mean = s * (1.0f / H);
      float inv = rsqrtf(sq * (1.0f / H) - mean * mean + 1e-5f);
      f32x4 a;
#pragma unroll
      for (int i = 0; i < 4; ++i) a[i] = fmaxf((vv[i] - mean) * inv * g1[i] + b1[i], 0.0f) + tv[i];
      s = a[0] + a[1] + a[2] + a[3];
      sq = a[0] * a[0] + a[1] * a[1] + a[2] * a[2] + a[3] * a[3];
#pragma unroll
      for (int st = 1; st < 64; st <<= 1) { s += __shfl_xor(s, st); sq += __shfl_xor(sq, st); }
      mean = s * (1.0f / H);
      inv = rsqrtf(sq * (1.0f / H) - mean * mean + 1e-5f);
      u16x4 ov;
#pragma unroll
      for (int i = 0; i < 4; ++i) {
        float n = (a[i] - mean) * inv * g2[i] + b2[i];
        ov[i] = f2bf(n * fsig(n));
      }
      *(u16x4*)&bout[(size_t)(m0 + row) * H + c0] = ov;
    }
  }
}

__global__ void k_gn_finalize(const double* __restrict__ sums, float* __restrict__ gstats) {
  int g = threadIdx.x;
  if (g < 32) {
    double s = 0.0, sq = 0.0;
    for (int c = g * 8; c < g * 8 + 8; ++c) {
      s += sums[c];
      sq += sums[H + c];
    }
    double n = 8.0 * (double)E_EDGES;
    double mean = s / n;
    double var = sq / n - mean * mean;
    gstats[g] = (float)mean;
    gstats[32 + g] = (float)(1.0 / sqrt(var + 1e-5));
  }
}

__global__ __launch_bounds__(256) void k_head(const unsigned short* __restrict__ e_bf,
                                              const float* __restrict__ gstats,
                                              const float* __restrict__ gn_g, const float* __restrict__ gn_b,
                                              const float* __restrict__ out_w, const float* __restrict__ out_b,
                                              float* __restrict__ out) {
  int wv = threadIdx.x >> 6;
  int lane = threadIdx.x & 63;
  int eid = blockIdx.x * 4 + wv;
  int c0 = lane * 4;
  u16x4 ev = *(const u16x4*)&e_bf[(size_t)eid * H + c0];
  float a0 = 0.0f, a1 = 0.0f;
#pragma unroll
  for (int i = 0; i < 4; ++i) {
    int c = c0 + i;
    int g = c >> 3;
    float v = (bf2f(ev[i]) - gstats[g]) * gstats[32 + g] * gn_g[c] + gn_b[c];
    v = fmaxf(v, 0.0f);
    a0 += v * out_w[c * 2 + 0];
    a1 += v * out_w[c * 2 + 1];
  }
  for (int s = 32; s > 0; s >>= 1) {
    a0 += __shfl_down(a0, s);
    a1 += __shfl_down(a1, s);
  }
  if (lane == 0) {
    out[(size_t)eid * 2 + 0] = a0 + out_b[0];
    out[(size_t)eid * 2 + 1] = a1 + out_b[1];
  }
}

// ---------------------------------------------------------------------------
extern "C" void kernel_launch(void* const* d_in, const int* in_sizes, int n_in,
                              void* d_out, int out_size, void* d_ws, size_t ws_size,
                              hipStream_t stream) {
  const float* nodes_feature = (const float*)d_in[0];
  const float* e_vals = (const float*)d_in[1];
  const int* mask = (const int*)d_in[2];
  const int* t = (const int*)d_in[3];
  const int* edge_index = (const int*)d_in[4];
  const float* node_w = (const float*)d_in[5];
  const float* node_b = (const float*)d_in[6];
  const float* edge_w = (const float*)d_in[7];
  const float* edge_b = (const float*)d_in[8];
  const float* te1_w = (const float*)d_in[9];
  const float* te1_b = (const float*)d_in[10];
  const float* te2_w = (const float*)d_in[11];
  const float* te2_b = (const float*)d_in[12];
  const float* U_w = (const float*)d_in[13];
  const float* U_b = (const float*)d_in[14];
  const float* V_w = (const float*)d_in[15];
  const float* V_b = (const float*)d_in[16];
  const float* A_w = (const float*)d_in[17];
  const float* A_b = (const float*)d_in[18];
  const float* B_w = (const float*)d_in[19];
  const float* B_b = (const float*)d_in[20];
  const float* C_w = (const float*)d_in[21];
  const float* C_b = (const float*)d_in[22];
  const float* nh_g = (const float*)d_in[23];
  const float* nh_b = (const float*)d_in[24];
  const float* ne_g = (const float*)d_in[25];
  const float* ne_b = (const float*)d_in[26];
  const float* tl_w = (const float*)d_in[27];
  const float* tl_b = (const float*)d_in[28];
  const float* plo_g = (const float*)d_in[29];
  const float* plo_b = (const float*)d_in[30];
  const float* plo_w = (const float*)d_in[31];
  const float* plo_b2 = (const float*)d_in[32];
  const float* gn_g = (const float*)d_in[33];
  const float* gn_b = (const float*)d_in[34];
  const float* out_w = (const float*)d_in[35];
  const float* out_b = (const float*)d_in[36];
  const float* mask_emb = (const float*)d_in[37];

  char* wsb = (char*)d_ws;
  size_t off = 0;
  auto alloc = [&](size_t bytes) -> void* {
    void* p = wsb + off;
    off += (bytes + 255) & ~(size_t)255;
    return p;
  };
  double* gn_sums = (double*)alloc(512 * sizeof(double));
  float* XW = (float*)alloc((size_t)V_NODES * 1024 * 4);
  unsigned short* e_bf = (unsigned short*)alloc((size_t)E_EDGES * H * 2);
  unsigned short* pe_b = (unsigned short*)alloc((size_t)E_EDGES * H * 2);
  unsigned short* x_bf = (unsigned short*)alloc((size_t)V_NODES * H * 2);
  unsigned short* WT4 = (unsigned short*)alloc((size_t)L_LAYERS * 1024 * H * 2);
  unsigned short* WTC = (unsigned short*)alloc((size_t)L_LAYERS * H * H * 2);
  unsigned short* WTplo = (unsigned short*)alloc((size_t)L_LAYERS * H * H * 2);
  unsigned short* WTedge = (unsigned short*)alloc((size_t)H * H * 2);
  float* b4 = (float*)alloc((size_t)L_LAYERS * 1024 * 4);
  float* tvec = (float*)alloc((size_t)L_LAYERS * H * 4);
  float* gstats = (float*)alloc(64 * 4);

  const int* ei_col = edge_index + E_EDGES;

  float* x = (float*)d_out;
  float* out2 = (float*)d_out + (size_t)V_NODES * H;

  // Merged preamble: prep_w | prep_b | node_embed | pe | temb+tvec
  k_pre<<<16192, 256, 0, stream>>>(U_w, V_w, A_w, B_w, C_w, plo_w, edge_w,
                                   WT4, WTC, WTplo, WTedge,
                                   U_b, V_b, A_b, B_b, b4,
                                   nodes_feature, node_w, node_b, x, x_bf,
                                   e_vals, pe_b,
                                   t, te1_w, te1_b, te2_w, te2_b, tl_w, tl_b, tvec);
  k_gemm<3, false><<<dim3(E_EDGES / 128, 2), 256, 0, stream>>>(pe_b, WTedge, E_EDGES, edge_b, mask, mask_emb,
                                                               nullptr, e_bf, nullptr);
  hipMemsetAsync(gn_sums, 0, 512 * sizeof(double), stream);

  for (int l = 0; l < L_LAYERS; ++l) {
    size_t wo = (size_t)l * H * H;
    size_t bo = (size_t)l * H;
    k_gemm0<<<dim3(24, 16), 256, 0, stream>>>(x_bf, WT4 + (size_t)l * 1024 * H, b4 + l * 1024, XW);
    k_layer_edge<<<E_EDGES / 32, 512, 0, stream>>>(e_bf, WTC + wo, C_b + bo, ei_col, XW,
                                                   nh_g + bo, nh_b + bo, ne_g + bo, ne_b + bo, tvec + bo,
                                                   plo_g + bo, plo_b + bo, x, x_bf, pe_b);
    if (l == L_LAYERS - 1) {
      k_gemm<2, true><<<dim3(E_EDGES / 128, 2), 256, 0, stream>>>(pe_b, WTplo + wo, E_EDGES, plo_b2 + bo,
                                                                  nullptr, nullptr, nullptr, e_bf, gn_sums);
    } else {
      k_gemm<2, false><<<dim3(E_EDGES / 128, 2), 256, 0, stream>>>(pe_b, WTplo + wo, E_EDGES, plo_b2 + bo,
                                                                   nullptr, nullptr, nullptr, e_bf, nullptr);
    }
  }

  k_gn_finalize<<<1, 64, 0, stream>>>(gn_sums, gstats);
  k_head<<<E_EDGES / 4, 256, 0, stream>>>(e_bf, gstats, gn_g, gn_b, out_w, out_b, out2);
}

// Round 12
// 747.605 us; speedup vs baseline: 1.1785x; 1.0241x over previous
//
#include <hip/hip_runtime.h>
#include <math.h>

#define V_NODES 3000
#define K_DEG 16
#define E_EDGES 48000
#define H 256
#define TE 128
#define L_LAYERS 12

typedef __attribute__((ext_vector_type(4))) float f32x4;
typedef __attribute__((ext_vector_type(8))) __bf16 bf16x8;
typedef __attribute__((ext_vector_type(4))) unsigned short u16x4;
typedef __attribute__((ext_vector_type(8))) unsigned short u16x8;

__device__ __forceinline__ unsigned short f2bf(float f) {
  unsigned u = __float_as_uint(f);
  unsigned r = (u + 0x7fffu + ((u >> 16) & 1u)) >> 16;
  return (unsigned short)r;
}

__device__ __forceinline__ float bf2f(unsigned short u) {
  return __uint_as_float(((unsigned)u) << 16);
}

// fast sigmoid via v_exp_f32 + v_rcp_f32 (~1e-6 rel err)
__device__ __forceinline__ float fsig(float x) {
  return __builtin_amdgcn_rcpf(1.0f + __builtin_amdgcn_exp2f(-1.4426950408889634f * x));
}

// HW sin/cos: v_sin_f32/v_cos_f32 take REVOLUTIONS (sin(x*2pi))
__device__ __forceinline__ float hsin(float rev) { return __builtin_amdgcn_sinf(rev); }
__device__ __forceinline__ float hcos(float rev) { return __builtin_amdgcn_cosf(rev); }

__device__ __forceinline__ void gload16(const void* g, void* l) {
  __builtin_amdgcn_global_load_lds((const __attribute__((address_space(1))) void*)g,
                                   (__attribute__((address_space(3))) void*)l, 16, 0, 0);
}

#define LG2_1E4 13.287712379549449f
#define INV_2PI 0.15915494309189535f

// ---------------------------------------------------------------------------
// Preamble (merged):
//  [0,1184)      prep_w (UVAB/C/plo/edge_w/node_w transposes -> bf16 WT)
//  [1184,1196)   prep_b
//  [1196,1946)   node sine embedding -> pe_node bf16 (4 nodes/block)
//  [1946,1958)   temb+tvec
// ---------------------------------------------------------------------------
__device__ void prep_w_body(char* ldsraw, int bid,
                            const float* __restrict__ U_w, const float* __restrict__ V_w,
                            const float* __restrict__ A_w, const float* __restrict__ B_w,
                            const float* __restrict__ C_w, const float* __restrict__ plo_w,
                            const float* __restrict__ edge_w, const float* __restrict__ node_w,
                            unsigned short* __restrict__ WT4, unsigned short* __restrict__ WTC,
                            unsigned short* __restrict__ WTplo, unsigned short* __restrict__ WTedge,
                            unsigned short* __restrict__ WTnode) {
  const float* src;
  unsigned short* dst;
  int tt;
  if (bid < 768) {
    int l = bid >> 6;
    int rem = bid & 63;
    int mat = rem >> 4;
    tt = rem & 15;
    const float* srcs[4] = {U_w, V_w, A_w, B_w};
    src = srcs[mat] + (size_t)l * H * H;
    dst = WT4 + (size_t)l * 1024 * H + (size_t)mat * H * H;
  } else if (bid < 960) {
    int b2 = bid - 768;
    int l = b2 >> 4;
    tt = b2 & 15;
    src = C_w + (size_t)l * H * H;
    dst = WTC + (size_t)l * H * H;
  } else if (bid < 1152) {
    int b2 = bid - 960;
    int l = b2 >> 4;
    tt = b2 & 15;
    src = plo_w + (size_t)l * H * H;
    dst = WTplo + (size_t)l * H * H;
  } else if (bid < 1168) {
    tt = bid - 1152;
    src = edge_w;
    dst = WTedge;
  } else {
    tt = bid - 1168;
    src = node_w;
    dst = WTnode;
  }
  int k0 = (tt & 3) * 64, n0 = (tt >> 2) * 64;
  float (*ts)[65] = (float(*)[65])ldsraw;
  int c = threadIdx.x & 63;
  int r0 = threadIdx.x >> 6;
  for (int rr = 0; rr < 64; rr += 4) {
    int r = rr + r0;
    ts[r][c] = src[(size_t)(k0 + r) * H + n0 + c];
  }
  __syncthreads();
  for (int nn = 0; nn < 64; nn += 4) {
    int n = nn + r0;
    dst[(size_t)(n0 + n) * H + k0 + c] = f2bf(ts[c][n]);
  }
}

__device__ void prep_b_body(int l,
                            const float* __restrict__ U_b, const float* __restrict__ V_b,
                            const float* __restrict__ A_b, const float* __restrict__ B_b,
                            float* __restrict__ b4) {
  int t = threadIdx.x;
  b4[l * 1024 + 0 + t] = U_b[l * H + t];
  b4[l * 1024 + 256 + t] = V_b[l * H + t];
  b4[l * 1024 + 512 + t] = A_b[l * H + t];
  b4[l * 1024 + 768 + t] = B_b[l * H + t];
}

__device__ void node_pe_body(int b, const float* __restrict__ coords, unsigned short* __restrict__ pe_node) {
  int v = b * 4 + (threadIdx.x >> 6);
  int lane = threadIdx.x & 63;
  int c0 = lane * 4;
  float cy = coords[v * 2 + 0];
  float cx = coords[v * 2 + 1];
  u16x4 ov;
#pragma unroll
  for (int i = 0; i < 4; ++i) {
    int c = c0 + i;
    int idx = c & 127;
    float coord = (c < 128) ? cy : cx;
    float invd = __builtin_amdgcn_exp2f(-(float)(idx & ~1) * (LG2_1E4 / 128.0f));
    float rev = coord * invd;  // coord*2pi/dim_t radians == coord/dim_t revolutions
    ov[i] = f2bf((idx & 1) ? hcos(rev) : hsin(rev));
  }
  *(u16x4*)&pe_node[(size_t)v * H + c0] = ov;
}

__device__ void temb_tvec_body(char* ldsraw, int l,
                               const int* __restrict__ t,
                               const float* __restrict__ te1_w, const float* __restrict__ te1_b,
                               const float* __restrict__ te2_w, const float* __restrict__ te2_b,
                               const float* __restrict__ tl_w, const float* __restrict__ tl_b,
                               float* __restrict__ tvec) {
  float* emb = (float*)ldsraw;
  float* h1 = (float*)(ldsraw + 1024);
  float* rt = (float*)(ldsraw + 1536);
  int j = threadIdx.x;
  float tv = (float)t[0];
  {
    int i = j & 127;
    float f = expf(-logf(10000.0f) * (float)i / 128.0f);
    float arg = tv * f;
    emb[j] = (j < 128) ? cosf(arg) : sinf(arg);
  }
  __syncthreads();
  if (j < TE) {
    float acc = te1_b[j];
    for (int k = 0; k < H; ++k) acc += emb[k] * te1_w[k * TE + j];
    h1[j] = fmaxf(acc, 0.0f);
  }
  __syncthreads();
  if (j < TE) {
    float acc = te2_b[j];
    for (int k = 0; k < TE; ++k) acc += h1[k] * te2_w[k * TE + j];
    rt[j] = fmaxf(acc, 0.0f);
  }
  __syncthreads();
  float acc = tl_b[l * H + j];
  for (int k = 0; k < TE; ++k) acc += rt[k] * tl_w[(size_t)(l * TE + k) * H + j];
  tvec[l * H + j] = acc;
}

__global__ __launch_bounds__(256) void k_pre(const float* __restrict__ U_w, const float* __restrict__ V_w,
                                             const float* __restrict__ A_w, const float* __restrict__ B_w,
                                             const float* __restrict__ C_w, const float* __restrict__ plo_w,
                                             const float* __restrict__ edge_w, const float* __restrict__ node_w,
                                             unsigned short* __restrict__ WT4, unsigned short* __restrict__ WTC,
                                             unsigned short* __restrict__ WTplo, unsigned short* __restrict__ WTedge,
                                             unsigned short* __restrict__ WTnode,
                                             const float* __restrict__ U_b, const float* __restrict__ V_b,
                                             const float* __restrict__ A_b, const float* __restrict__ B_b,
                                             float* __restrict__ b4,
                                             const float* __restrict__ coords, unsigned short* __restrict__ pe_node,
                                             const int* __restrict__ t,
                                             const float* __restrict__ te1_w, const float* __restrict__ te1_b,
                                             const float* __restrict__ te2_w, const float* __restrict__ te2_b,
                                             const float* __restrict__ tl_w, const float* __restrict__ tl_b,
                                             float* __restrict__ tvec) {
  __shared__ __align__(16) char lds[16896];
  int b = blockIdx.x;
  if (b < 1184) {
    prep_w_body(lds, b, U_w, V_w, A_w, B_w, C_w, plo_w, edge_w, node_w, WT4, WTC, WTplo, WTedge, WTnode);
  } else if (b < 1196) {
    prep_b_body(b - 1184, U_b, V_b, A_b, B_b, b4);
  } else if (b < 1946) {
    node_pe_body(b - 1196, coords, pe_node);
  } else {
    temb_tvec_body(lds, b - 1946, t, te1_w, te1_b, te2_w, te2_b, tl_w, tl_b, tvec);
  }
}

// ---------------------------------------------------------------------------
// MFMA GEMM (128x128 tile, 4 waves, BK=64).
// MODE 2: edge plo  -> e_bf += acc + bias; GN: fused stats
// MODE 3: edge embed-> A generated IN-REGISTER (sine PE from e_vals) -> LDS;
//                      out = acc + bias + mask_emb[mask[m]] -> e_bf
// MODE 4: node embed-> out x f32 [m*256+n] + x_bf (M-guarded)
// ---------------------------------------------------------------------------
template <int MODE, bool GN>
__global__ __launch_bounds__(256) void k_gemm(const unsigned short* __restrict__ A,
                                              const unsigned short* __restrict__ WT,
                                              int M,
                                              const float* __restrict__ bias,
                                              const int* __restrict__ maskp,
                                              const float* __restrict__ mask_emb,
                                              const float* __restrict__ e_vals,
                                              float* __restrict__ out_f32,
                                              unsigned short* __restrict__ out_bf16,
                                              double* __restrict__ gnp) {
  const int t = threadIdx.x;
  const int m0 = blockIdx.x * 128;
  const int nb = blockIdx.y * 128;
  const int lane = t & 63;
  const int wave = t >> 6;
  const int wr = wave >> 1, wc = wave & 1;
  const int lrow = lane & 15, lg = lane >> 4;

  __shared__ __align__(16) char lds[32768];
  char* Als = lds;
  char* Bls = lds + 16384;

  f32x4 acc[4][4];
#pragma unroll
  for (int i = 0; i < 4; ++i)
#pragma unroll
    for (int j = 0; j < 4; ++j) acc[i][j] = (f32x4)0.0f;

  for (int kt = 0; kt < 4; ++kt) {
    const int k0b = kt * 128;
#pragma unroll
    for (int i = 0; i < 4; ++i) {
      int o = i * 4096 + t * 16;
      int row = o >> 7;
      int cb = o & 127;
      int cbl = cb ^ ((row & 7) << 4);
      if constexpr (MODE == 3) {
        // Generate 8 bf16 sine-PE values for edge m0+row, channels ch0..ch0+7,
        // directly at the swizzled-linear LDS slot gload16 would have filled.
        float val = e_vals[m0 + row];
        int ch0 = (k0b + cbl) >> 1;
        u16x8 ov;
#pragma unroll
        for (int p = 0; p < 4; ++p) {
          int c = ch0 + 2 * p;
          float invd = __builtin_amdgcn_exp2f(-(float)c * (LG2_1E4 / 256.0f));
          float rev = val * invd * INV_2PI;
          ov[2 * p] = f2bf(hsin(rev));
          ov[2 * p + 1] = f2bf(hcos(rev));
        }
        *(u16x8*)(Als + o) = ov;
      } else {
        int rA = m0 + row;
        rA = rA < M ? rA : 0;
        gload16((const char*)A + (size_t)rA * 512 + k0b + cbl,
                Als + i * 4096 + (t & 192) * 16);
      }
      gload16((const char*)WT + (size_t)(nb + row) * 512 + k0b + cbl,
              Bls + i * 4096 + (t & 192) * 16);
    }
    __syncthreads();
#pragma unroll
    for (int ks = 0; ks < 2; ++ks) {
      bf16x8 af[4], bfv[4];
#pragma unroll
      for (int mi = 0; mi < 4; ++mi) {
        int ra = wr * 64 + mi * 16 + lrow;
        int cba = (ks * 64 + lg * 16) ^ ((ra & 7) << 4);
        af[mi] = *(const bf16x8*)(Als + ra * 128 + cba);
        int rb = wc * 64 + mi * 16 + lrow;
        int cbb = (ks * 64 + lg * 16) ^ ((rb & 7) << 4);
        bfv[mi] = *(const bf16x8*)(Bls + rb * 128 + cbb);
      }
#pragma unroll
      for (int mi = 0; mi < 4; ++mi)
#pragma unroll
        for (int ni = 0; ni < 4; ++ni)
          acc[mi][ni] = __builtin_amdgcn_mfma_f32_16x16x32_bf16(af[mi], bfv[ni], acc[mi][ni], 0, 0, 0);
    }
    __syncthreads();
  }

  double ps[4] = {0, 0, 0, 0}, pq[4] = {0, 0, 0, 0};
#pragma unroll
  for (int mi = 0; mi < 4; ++mi) {
#pragma unroll
    for (int r = 0; r < 4; ++r) {
      int m = m0 + wr * 64 + mi * 16 + lg * 4 + r;
      if (MODE == 4 && m >= M) continue;
      int mk = 0;
      if constexpr (MODE == 3) { mk = maskp[m]; }
#pragma unroll
      for (int ni = 0; ni < 4; ++ni) {
        int n = nb + wc * 64 + ni * 16 + lrow;
        float v = acc[mi][ni][r] + bias[n];
        if constexpr (MODE == 2) {
          float eo = bf2f(out_bf16[(size_t)m * 256 + n]);
          unsigned short nb16 = f2bf(eo + v);
          out_bf16[(size_t)m * 256 + n] = nb16;
          if constexpr (GN) {
            float rv = bf2f(nb16);
            ps[ni] += (double)rv;
            pq[ni] += (double)rv * (double)rv;
          }
        } else if constexpr (MODE == 3) {
          v += mask_emb[mk * 256 + n];
          out_bf16[(size_t)m * 256 + n] = f2bf(v);
        } else {  // MODE 4
          out_f32[(size_t)m * 256 + n] = v;
          out_bf16[(size_t)m * 256 + n] = f2bf(v);
        }
      }
    }
  }

  if constexpr (GN) {
    __syncthreads();
    double* redS = (double*)lds;           // [128][8] f64 = 8KB
    double* redQ = (double*)(lds + 8192);  // 8KB
    int slot = wr * 4 + lg;
#pragma unroll
    for (int ni = 0; ni < 4; ++ni) {
      int cn = wc * 64 + ni * 16 + lrow;
      redS[cn * 8 + slot] = ps[ni];
      redQ[cn * 8 + slot] = pq[ni];
    }
    __syncthreads();
    if (t < 128) {
      double s = 0, q = 0;
#pragma unroll
      for (int k = 0; k < 8; ++k) { s += redS[t * 8 + k]; q += redQ[t * 8 + k]; }
      atomicAdd(&gnp[nb + t], s);
      atomicAdd(&gnp[H + nb + t], q);
    }
  }
}

// ---------------------------------------------------------------------------
// Node UVAB GEMM: BM=128, BN=64, BK=64, 4 waves; grid (24,16) = 384 blocks
// ---------------------------------------------------------------------------
__global__ __launch_bounds__(256) void k_gemm0(const unsigned short* __restrict__ A,
                                               const unsigned short* __restrict__ WT,
                                               const float* __restrict__ bias,
                                               float* __restrict__ out_f32) {
  const int t = threadIdx.x;
  const int m0 = blockIdx.x * 128;
  const int nb = blockIdx.y * 64;
  const int lane = t & 63;
  const int wave = t >> 6;
  const int lrow = lane & 15, lg = lane >> 4;

  __shared__ __align__(16) char lds[24576];
  char* Als = lds;           // [128][128B] swizzled
  char* Bls = lds + 16384;   // [64][128B] swizzled

  f32x4 acc[2][4];
#pragma unroll
  for (int i = 0; i < 2; ++i)
#pragma unroll
    for (int j = 0; j < 4; ++j) acc[i][j] = (f32x4)0.0f;

  for (int kt = 0; kt < 4; ++kt) {
    const int k0b = kt * 128;
#pragma unroll
    for (int i = 0; i < 4; ++i) {  // A: 128 rows x 128B = 16KB
      int o = i * 4096 + t * 16;
      int row = o >> 7;
      int cbl = (o & 127) ^ ((row & 7) << 4);
      int rA = m0 + row;
      rA = rA < V_NODES ? rA : 0;
      gload16((const char*)A + (size_t)rA * 512 + k0b + cbl,
              Als + i * 4096 + (t & 192) * 16);
    }
#pragma unroll
    for (int c = 0; c < 2; ++c) {  // B: 64 rows x 128B = 8KB
      int o = c * 4096 + t * 16;
      int row = o >> 7;
      int cbl = (o & 127) ^ ((row & 7) << 4);
      gload16((const char*)WT + (size_t)(nb + row) * 512 + k0b + cbl,
              Bls + c * 4096 + (t & 192) * 16);
    }
    __syncthreads();
#pragma unroll
    for (int ks = 0; ks < 2; ++ks) {
      bf16x8 af[2], bfv[4];
#pragma unroll
      for (int mi = 0; mi < 2; ++mi) {
        int ra = wave * 32 + mi * 16 + lrow;
        af[mi] = *(const bf16x8*)(Als + ra * 128 + ((ks * 64 + lg * 16) ^ ((ra & 7) << 4)));
      }
#pragma unroll
      for (int ni = 0; ni < 4; ++ni) {
        int rb = ni * 16 + lrow;
        bfv[ni] = *(const bf16x8*)(Bls + rb * 128 + ((ks * 64 + lg * 16) ^ ((rb & 7) << 4)));
      }
#pragma unroll
      for (int mi = 0; mi < 2; ++mi)
#pragma unroll
        for (int ni = 0; ni < 4; ++ni)
          acc[mi][ni] = __builtin_amdgcn_mfma_f32_16x16x32_bf16(af[mi], bfv[ni], acc[mi][ni], 0, 0, 0);
    }
    __syncthreads();
  }

#pragma unroll
  for (int mi = 0; mi < 2; ++mi) {
#pragma unroll
    for (int r = 0; r < 4; ++r) {
      int m = m0 + wave * 32 + mi * 16 + lg * 4 + r;
      if (m >= V_NODES) continue;
#pragma unroll
      for (int ni = 0; ni < 4; ++ni) {
        int n = nb + ni * 16 + lrow;
        out_f32[(size_t)m * 1024 + n] = acc[mi][ni][r] + bias[n];
      }
    }
  }
}

// ---------------------------------------------------------------------------
// Fused layer-edge kernel: BM=32 (2 nodes), BN=256, 8 waves (512 thr).
// ---------------------------------------------------------------------------
__global__ __launch_bounds__(512, 8) void k_layer_edge(const unsigned short* __restrict__ A,
                                                       const unsigned short* __restrict__ WT,
                                                       const float* __restrict__ Cb,
                                                       const int* __restrict__ ei_col,
                                                       const float* __restrict__ XW,
                                                       const float* __restrict__ nhg, const float* __restrict__ nhb,
                                                       const float* __restrict__ neg_, const float* __restrict__ neb_,
                                                       const float* __restrict__ tvec_l,
                                                       const float* __restrict__ pg_, const float* __restrict__ pb_,
                                                       float* __restrict__ x, unsigned short* __restrict__ xb,
                                                       unsigned short* __restrict__ bout) {
  const int t = threadIdx.x;
  const int m0 = blockIdx.x * 32;
  const int lane = t & 63;
  const int wave = t >> 6;      // 8 col-groups of 32 cols each
  const int wc = wave;
  const int lrow = lane & 15, lg = lane >> 4;
  const int c0 = lane * 4;

  __shared__ __align__(16) char lds[36864];
  char* Als = lds;            // [32][128B] swizzled (GEMM phase)
  char* Bls = lds + 4096;     // [256][128B] swizzled (GEMM phase)
  float* enew = (float*)lds;  // [32][256] f32 swizzled (epilogue)

  f32x4 acc[2][2];
#pragma unroll
  for (int i = 0; i < 2; ++i)
#pragma unroll
    for (int j = 0; j < 2; ++j) acc[i][j] = (f32x4)0.0f;

  const int wave_off = wave * 1024;
  for (int kt = 0; kt < 4; ++kt) {
    const int k0b = kt * 128;
    if (t < 256) {  // A: 32 rows x 128B = 4KB
      int o = t * 16;
      int row = o >> 7;
      int cbl = (o & 127) ^ ((row & 7) << 4);
      gload16((const char*)A + (size_t)(m0 + row) * 512 + k0b + cbl, Als + wave_off);
    }
#pragma unroll
    for (int c = 0; c < 4; ++c) {  // B: 256 rows x 128B = 32KB
      int o = c * 8192 + t * 16;
      int row = o >> 7;
      int cbl = (o & 127) ^ ((row & 7) << 4);
      gload16((const char*)WT + (size_t)row * 512 + k0b + cbl, Bls + c * 8192 + wave_off);
    }
    __syncthreads();
#pragma unroll
    for (int ks = 0; ks < 2; ++ks) {
      bf16x8 af[2], bfv[2];
#pragma unroll
      for (int mi = 0; mi < 2; ++mi) {
        int ra = mi * 16 + lrow;
        af[mi] = *(const bf16x8*)(Als + ra * 128 + ((ks * 64 + lg * 16) ^ ((ra & 7) << 4)));
      }
#pragma unroll
      for (int ni = 0; ni < 2; ++ni) {
        int rb = wc * 32 + ni * 16 + lrow;
        bfv[ni] = *(const bf16x8*)(Bls + rb * 128 + ((ks * 64 + lg * 16) ^ ((rb & 7) << 4)));
      }
#pragma unroll
      for (int mi = 0; mi < 2; ++mi)
#pragma unroll
        for (int ni = 0; ni < 2; ++ni)
          acc[mi][ni] = __builtin_amdgcn_mfma_f32_16x16x32_bf16(af[mi], bfv[ni], acc[mi][ni], 0, 0, 0);
    }
    __syncthreads();
  }

  // ---- E0: acc + Cb + Ah[col] + Bh[node] -> enew (swizzled f32) ----
  {
    float bs[2];
#pragma unroll
    for (int ni = 0; ni < 2; ++ni) bs[ni] = Cb[wc * 32 + ni * 16 + lrow];
#pragma unroll
    for (int mi = 0; mi < 2; ++mi) {
#pragma unroll
      for (int r = 0; r < 4; ++r) {
        int ml = mi * 16 + lg * 4 + r;
        int m = m0 + ml;
        int cv = ei_col[m];
        const float* AhR = XW + (size_t)cv * 1024 + 512;
        const float* BhR = XW + (size_t)(m >> 4) * 1024 + 768;
        int sw = (ml & 15) << 2;
#pragma unroll
        for (int ni = 0; ni < 2; ++ni) {
          int n = wc * 32 + ni * 16 + lrow;
          enew[ml * 256 + (n ^ sw)] = acc[mi][ni][r] + bs[ni] + AhR[n] + BhR[n];
        }
      }
    }
  }
  __syncthreads();

  // ---- E1: node update (waves 0-1, one node each) ----
  if (wave < 2) {
    int v = (m0 >> 4) + wave;
    f32x4 agg = (f32x4)0.0f;
#pragma unroll 4
    for (int k = 0; k < K_DEG; ++k) {
      int row = wave * 16 + k;
      int cv = ei_col[m0 + row];
      f32x4 en = *(const f32x4*)&enew[row * 256 + (c0 ^ ((row & 15) << 2))];
      f32x4 vh = *(const f32x4*)&XW[(size_t)cv * 1024 + 256 + c0];
#pragma unroll
      for (int i = 0; i < 4; ++i) agg[i] += vh[i] * fsig(en[i]);
    }
    f32x4 s4 = *(const f32x4*)&XW[(size_t)v * 1024 + c0];  // Uh
    s4 += agg;
    float s = s4[0] + s4[1] + s4[2] + s4[3];
    float sq = s4[0] * s4[0] + s4[1] * s4[1] + s4[2] * s4[2] + s4[3] * s4[3];
#pragma unroll
    for (int st = 1; st < 64; st <<= 1) { s += __shfl_xor(s, st); sq += __shfl_xor(sq, st); }
    float mean = s * (1.0f / H);
    float inv = rsqrtf(sq * (1.0f / H) - mean * mean + 1e-5f);
    f32x4 g = *(const f32x4*)&nhg[c0];
    f32x4 bb = *(const f32x4*)&nhb[c0];
    f32x4 xo = *(const f32x4*)&x[(size_t)v * H + c0];
    u16x4 ov;
#pragma unroll
    for (int i = 0; i < 4; ++i) {
      float h = fmaxf((s4[i] - mean) * inv * g[i] + bb[i], 0.0f);
      xo[i] += h;
      ov[i] = f2bf(xo[i]);
    }
    *(f32x4*)&x[(size_t)v * H + c0] = xo;
    *(u16x4*)&xb[(size_t)v * H + c0] = ov;
  }

  // ---- E2: double-LN + silu chain -> bout bf16 (4 rows per wave) ----
  {
    f32x4 g1 = *(const f32x4*)&neg_[c0];
    f32x4 b1 = *(const f32x4*)&neb_[c0];
    f32x4 tv = *(const f32x4*)&tvec_l[c0];
    f32x4 g2 = *(const f32x4*)&pg_[c0];
    f32x4 b2 = *(const f32x4*)&pb_[c0];
#pragma unroll
    for (int k = 0; k < 4; ++k) {
      int row = wave + 8 * k;
      f32x4 vv = *(const f32x4*)&enew[row * 256 + (c0 ^ ((row & 15) << 2))];
      float s = vv[0] + vv[1] + vv[2] + vv[3];
      float sq = vv[0] * vv[0] + vv[1] * vv[1] + vv[2] * vv[2] + vv[3] * vv[3];
#pragma unroll
      for (int st = 1; st < 64; st <<= 1) { s += __shfl_xor(s, st); sq += __shfl_xor(sq, st); }
      float mean = s * (1.0f / H);
      float inv = rsqrtf(sq * (1.0f / H) - mean * mean + 1e-5f);
      f32x4 a;
#pragma unroll
      for (int i = 0; i < 4; ++i) a[i] = fmaxf((vv[i] - mean) * inv * g1[i] + b1[i], 0.0f) + tv[i];
      s = a[0] + a[1] + a[2] + a[3];
      sq = a[0] * a[0] + a[1] * a[1] + a[2] * a[2] + a[3] * a[3];
#pragma unroll
      for (int st = 1; st < 64; st <<= 1) { s += __shfl_xor(s, st); sq += __shfl_xor(sq, st); }
      mean = s * (1.0f / H);
      inv = rsqrtf(sq * (1.0f / H) - mean * mean + 1e-5f);
      u16x4 ov;
#pragma unroll
      for (int i = 0; i < 4; ++i) {
        float n = (a[i] - mean) * inv * g2[i] + b2[i];
        ov[i] = f2bf(n * fsig(n));
      }
      *(u16x4*)&bout[(size_t)(m0 + row) * H + c0] = ov;
    }
  }
}

__global__ void k_gn_finalize(const double* __restrict__ sums, float* __restrict__ gstats) {
  int g = threadIdx.x;
  if (g < 32) {
    double s = 0.0, sq = 0.0;
    for (int c = g * 8; c < g * 8 + 8; ++c) {
      s += sums[c];
      sq += sums[H + c];
    }
    double n = 8.0 * (double)E_EDGES;
    double mean = s / n;
    double var = sq / n - mean * mean;
    gstats[g] = (float)mean;
    gstats[32 + g] = (float)(1.0 / sqrt(var + 1e-5));
  }
}

__global__ __launch_bounds__(256) void k_head(const unsigned short* __restrict__ e_bf,
                                              const float* __restrict__ gstats,
                                              const float* __restrict__ gn_g, const float* __restrict__ gn_b,
                                              const float* __restrict__ out_w, const float* __restrict__ out_b,
                                              float* __restrict__ out) {
  int wv = threadIdx.x >> 6;
  int lane = threadIdx.x & 63;
  int eid = blockIdx.x * 4 + wv;
  int c0 = lane * 4;
  u16x4 ev = *(const u16x4*)&e_bf[(size_t)eid * H + c0];
  float a0 = 0.0f, a1 = 0.0f;
#pragma unroll
  for (int i = 0; i < 4; ++i) {
    int c = c0 + i;
    int g = c >> 3;
    float v = (bf2f(ev[i]) - gstats[g]) * gstats[32 + g] * gn_g[c] + gn_b[c];
    v = fmaxf(v, 0.0f);
    a0 += v * out_w[c * 2 + 0];
    a1 += v * out_w[c * 2 + 1];
  }
  for (int s = 32; s > 0; s >>= 1) {
    a0 += __shfl_down(a0, s);
    a1 += __shfl_down(a1, s);
  }
  if (lane == 0) {
    out[(size_t)eid * 2 + 0] = a0 + out_b[0];
    out[(size_t)eid * 2 + 1] = a1 + out_b[1];
  }
}

// ---------------------------------------------------------------------------
extern "C" void kernel_launch(void* const* d_in, const int* in_sizes, int n_in,
                              void* d_out, int out_size, void* d_ws, size_t ws_size,
                              hipStream_t stream) {
  const float* nodes_feature = (const float*)d_in[0];
  const float* e_vals = (const float*)d_in[1];
  const int* mask = (const int*)d_in[2];
  const int* t = (const int*)d_in[3];
  const int* edge_index = (const int*)d_in[4];
  const float* node_w = (const float*)d_in[5];
  const float* node_b = (const float*)d_in[6];
  const float* edge_w = (const float*)d_in[7];
  const float* edge_b = (const float*)d_in[8];
  const float* te1_w = (const float*)d_in[9];
  const float* te1_b = (const float*)d_in[10];
  const float* te2_w = (const float*)d_in[11];
  const float* te2_b = (const float*)d_in[12];
  const float* U_w = (const float*)d_in[13];
  const float* U_b = (const float*)d_in[14];
  const float* V_w = (const float*)d_in[15];
  const float* V_b = (const float*)d_in[16];
  const float* A_w = (const float*)d_in[17];
  const float* A_b = (const float*)d_in[18];
  const float* B_w = (const float*)d_in[19];
  const float* B_b = (const float*)d_in[20];
  const float* C_w = (const float*)d_in[21];
  const float* C_b = (const float*)d_in[22];
  const float* nh_g = (const float*)d_in[23];
  const float* nh_b = (const float*)d_in[24];
  const float* ne_g = (const float*)d_in[25];
  const float* ne_b = (const float*)d_in[26];
  const float* tl_w = (const float*)d_in[27];
  const float* tl_b = (const float*)d_in[28];
  const float* plo_g = (const float*)d_in[29];
  const float* plo_b = (const float*)d_in[30];
  const float* plo_w = (const float*)d_in[31];
  const float* plo_b2 = (const float*)d_in[32];
  const float* gn_g = (const float*)d_in[33];
  const float* gn_b = (const float*)d_in[34];
  const float* out_w = (const float*)d_in[35];
  const float* out_b = (const float*)d_in[36];
  const float* mask_emb = (const float*)d_in[37];

  char* wsb = (char*)d_ws;
  size_t off = 0;
  auto alloc = [&](size_t bytes) -> void* {
    void* p = wsb + off;
    off += (bytes + 255) & ~(size_t)255;
    return p;
  };
  double* gn_sums = (double*)alloc(512 * sizeof(double));
  float* XW = (float*)alloc((size_t)V_NODES * 1024 * 4);
  unsigned short* e_bf = (unsigned short*)alloc((size_t)E_EDGES * H * 2);
  unsigned short* pe_b = (unsigned short*)alloc((size_t)E_EDGES * H * 2);  // bout buffer
  unsigned short* x_bf = (unsigned short*)alloc((size_t)V_NODES * H * 2);
  unsigned short* pe_node = (unsigned short*)alloc((size_t)V_NODES * H * 2);
  unsigned short* WT4 = (unsigned short*)alloc((size_t)L_LAYERS * 1024 * H * 2);
  unsigned short* WTC = (unsigned short*)alloc((size_t)L_LAYERS * H * H * 2);
  unsigned short* WTplo = (unsigned short*)alloc((size_t)L_LAYERS * H * H * 2);
  unsigned short* WTedge = (unsigned short*)alloc((size_t)H * H * 2);
  unsigned short* WTnode = (unsigned short*)alloc((size_t)H * H * 2);
  float* b4 = (float*)alloc((size_t)L_LAYERS * 1024 * 4);
  float* tvec = (float*)alloc((size_t)L_LAYERS * H * 4);
  float* gstats = (float*)alloc(64 * 4);

  const int* ei_col = edge_index + E_EDGES;

  float* x = (float*)d_out;
  float* out2 = (float*)d_out + (size_t)V_NODES * H;

  // Merged preamble: prep_w | prep_b | node sine PE | temb+tvec
  k_pre<<<1958, 256, 0, stream>>>(U_w, V_w, A_w, B_w, C_w, plo_w, edge_w, node_w,
                                  WT4, WTC, WTplo, WTedge, WTnode,
                                  U_b, V_b, A_b, B_b, b4,
                                  nodes_feature, pe_node,
                                  t, te1_w, te1_b, te2_w, te2_b, tl_w, tl_b, tvec);
  // Node embed GEMM: x = pe_node @ node_w + node_b (f32 x + bf16 x_bf)
  k_gemm<4, false><<<dim3(24, 2), 256, 0, stream>>>(pe_node, WTnode, V_NODES, node_b, nullptr, nullptr,
                                                    nullptr, x, x_bf, nullptr);
  // Edge embed GEMM: PE generated in-register
  k_gemm<3, false><<<dim3(E_EDGES / 128, 2), 256, 0, stream>>>(nullptr, WTedge, E_EDGES, edge_b, mask, mask_emb,
                                                               e_vals, nullptr, e_bf, nullptr);
  hipMemsetAsync(gn_sums, 0, 512 * sizeof(double), stream);

  for (int l = 0; l < L_LAYERS; ++l) {
    size_t wo = (size_t)l * H * H;
    size_t bo = (size_t)l * H;
    k_gemm0<<<dim3(24, 16), 256, 0, stream>>>(x_bf, WT4 + (size_t)l * 1024 * H, b4 + l * 1024, XW);
    k_layer_edge<<<E_EDGES / 32, 512, 0, stream>>>(e_bf, WTC + wo, C_b + bo, ei_col, XW,
                                                   nh_g + bo, nh_b + bo, ne_g + bo, ne_b + bo, tvec + bo,
                                                   plo_g + bo, plo_b + bo, x, x_bf, pe_b);
    if (l == L_LAYERS - 1) {
      k_gemm<2, true><<<dim3(E_EDGES / 128, 2), 256, 0, stream>>>(pe_b, WTplo + wo, E_EDGES, plo_b2 + bo,
                                                                  nullptr, nullptr, nullptr, nullptr, e_bf, gn_sums);
    } else {
      k_gemm<2, false><<<dim3(E_EDGES / 128, 2), 256, 0, stream>>>(pe_b, WTplo + wo, E_EDGES, plo_b2 + bo,
                                                                   nullptr, nullptr, nullptr, nullptr, e_bf, nullptr);
    }
  }

  k_gn_finalize<<<1, 64, 0, stream>>>(gn_sums, gstats);
  k_head<<<E_EDGES / 4, 256, 0, stream>>>(e_bf, gstats, gn_g, gn_b, out_w, out_b, out2);
}